// Round 1
// baseline (239.888 us; speedup 1.0000x reference)
//
#include <hip/hip_runtime.h>

#define D_MODEL 256
#define NHEADS 4
#define DHEAD 64
#define BATCH 4
#define TSEQ 2048
#define CHUNK 64
#define NCHUNK (TSEQ / CHUNK)   // 32
#define NTOK (BATCH * TSEQ)     // 8192
#define NBH (BATCH * NHEADS)    // 16
#define EPSV 1e-6f
#define ROWS 16

// elu(a) + 1  ==  a+1 (a>0)  else exp(a)
__device__ __forceinline__ float elu1(float a) {
    return a > 0.0f ? a + 1.0f : __expf(a);
}

__device__ __forceinline__ void fma4(float4& o, float a, const float4& v) {
    o.x = fmaf(a, v.x, o.x);
    o.y = fmaf(a, v.y, o.y);
    o.z = fmaf(a, v.z, o.z);
    o.w = fmaf(a, v.w, o.w);
}

// zero components i of a (A[t0+i][s]) where s > t0+i (causal mask)
__device__ __forceinline__ void mask4(float4& a, int s, int t0) {
    if (s > t0 + 0) a.x = 0.f;
    if (s > t0 + 1) a.y = 0.f;
    if (s > t0 + 2) a.z = 0.f;
    if (s > t0 + 3) a.w = 0.f;
}

// ---------------------------------------------------------------------------
// Kernel 1: Q = elu1(x@Wq+bq), K = elu1(x@Wk+bk), V = x@Wv+bv
// One block computes ROWS rows; thread tid owns output column `tid` of all 3.
// x-row reads are wave-uniform (scalar cache); W reads coalesced.
// ---------------------------------------------------------------------------
__global__ __launch_bounds__(256) void qkv_kernel(
    const float* __restrict__ x,
    const float* __restrict__ Wq, const float* __restrict__ bq,
    const float* __restrict__ Wk, const float* __restrict__ bk,
    const float* __restrict__ Wv, const float* __restrict__ bv,
    float* __restrict__ Q, float* __restrict__ K, float* __restrict__ V)
{
    const int tid = threadIdx.x;
    const int row0 = blockIdx.x * ROWS;
    float aq[ROWS], ak[ROWS], av[ROWS];
    const float bqv = bq[tid], bkv = bk[tid], bvv = bv[tid];
#pragma unroll
    for (int r = 0; r < ROWS; ++r) { aq[r] = bqv; ak[r] = bkv; av[r] = bvv; }
    const float* xrow = x + (size_t)row0 * D_MODEL;
    for (int k = 0; k < D_MODEL; ++k) {
        const float wq = Wq[k * D_MODEL + tid];
        const float wk = Wk[k * D_MODEL + tid];
        const float wv = Wv[k * D_MODEL + tid];
#pragma unroll
        for (int r = 0; r < ROWS; ++r) {
            const float xv = xrow[r * D_MODEL + k];   // uniform -> s_load
            aq[r] = fmaf(xv, wq, aq[r]);
            ak[r] = fmaf(xv, wk, ak[r]);
            av[r] = fmaf(xv, wv, av[r]);
        }
    }
#pragma unroll
    for (int r = 0; r < ROWS; ++r) {
        const int o = (row0 + r) * D_MODEL + tid;
        Q[o] = elu1(aq[r]);
        K[o] = elu1(ak[r]);
        V[o] = av[r];
    }
}

// ---------------------------------------------------------------------------
// Kernel 2: per-chunk KV_c[d][m] = sum_t K[t][d]*V[t][m]   (64x64)
//           Z_c[d]   = sum_t K[t][d]
// One block per (b,h,chunk). 4x4 register tile per thread, float4 LDS reads.
// ---------------------------------------------------------------------------
__global__ __launch_bounds__(256) void chunksum_kernel(
    const float* __restrict__ K, const float* __restrict__ V,
    float* __restrict__ KVc, float* __restrict__ Zc)
{
    const int tid = threadIdx.x;
    const int c  = blockIdx.x % NCHUNK;
    const int bh = blockIdx.x / NCHUNK;
    const int b = bh / NHEADS, h = bh % NHEADS;

    __shared__ float Ks[CHUNK][DHEAD + 4];  // stride 68: 16B-aligned, conflict-free
    __shared__ float Vs[CHUNK][DHEAD];

    const size_t gbase = ((size_t)(b * TSEQ + c * CHUNK)) * D_MODEL + h * DHEAD;
#pragma unroll
    for (int i = 0; i < 16; ++i) {
        const int idx = i * 256 + tid;
        const int t = idx >> 6, d = idx & 63;
        Ks[t][d] = K[gbase + (size_t)t * D_MODEL + d];
        Vs[t][d] = V[gbase + (size_t)t * D_MODEL + d];
    }
    __syncthreads();

    const int ty = tid >> 4, tx = tid & 15;
    const int d0 = ty * 4, m0 = tx * 4;
    float4 o0 = {0,0,0,0}, o1 = o0, o2 = o0, o3 = o0;
    for (int t = 0; t < CHUNK; ++t) {
        const float4 k4 = *reinterpret_cast<const float4*>(&Ks[t][d0]);
        const float4 v4 = *reinterpret_cast<const float4*>(&Vs[t][m0]);
        fma4(o0, k4.x, v4);
        fma4(o1, k4.y, v4);
        fma4(o2, k4.z, v4);
        fma4(o3, k4.w, v4);
    }
    float* kvb = KVc + (size_t)blockIdx.x * (DHEAD * DHEAD);
    *reinterpret_cast<float4*>(&kvb[(d0 + 0) * DHEAD + m0]) = o0;
    *reinterpret_cast<float4*>(&kvb[(d0 + 1) * DHEAD + m0]) = o1;
    *reinterpret_cast<float4*>(&kvb[(d0 + 2) * DHEAD + m0]) = o2;
    *reinterpret_cast<float4*>(&kvb[(d0 + 3) * DHEAD + m0]) = o3;

    if (tid < DHEAD) {
        float z = 0.f;
        for (int t = 0; t < CHUNK; ++t) z += Ks[t][tid];
        Zc[(size_t)blockIdx.x * DHEAD + tid] = z;
    }
}

// ---------------------------------------------------------------------------
// Kernel 3: in-place EXCLUSIVE prefix sum over chunks, per (b,h), per element.
// Blocks [0,256): KV elements (one thread per element scan).
// Blocks [256,260): Z elements.
// ---------------------------------------------------------------------------
__global__ __launch_bounds__(256) void prefix_kernel(
    float* __restrict__ KVc, float* __restrict__ Zc)
{
    const int tid = threadIdx.x;
    if (blockIdx.x < NBH * 16) {
        const int bh = blockIdx.x >> 4;
        const int e = ((blockIdx.x & 15) << 8) + tid;   // 0..4095
        float s = 0.f;
        for (int c = 0; c < NCHUNK; ++c) {
            const size_t idx = ((size_t)(bh * NCHUNK + c)) * (DHEAD * DHEAD) + e;
            const float v = KVc[idx];
            KVc[idx] = s;
            s += v;
        }
    } else {
        const int j = ((int)(blockIdx.x - NBH * 16) << 8) + tid;  // 0..1023
        if (j < NBH * DHEAD) {
            const int bh = j >> 6, d = j & 63;
            float s = 0.f;
            for (int c = 0; c < NCHUNK; ++c) {
                const int idx = (bh * NCHUNK + c) * DHEAD + d;
                const float v = Zc[idx];
                Zc[idx] = s;
                s += v;
            }
        }
    }
}

// ---------------------------------------------------------------------------
// Kernel 4: per-chunk output.
//   A = tril(Q K^T)                       (64x64, within chunk)
//   O[t][m] = (sum_d Q[t][d]*Sprev[d][m] + sum_s A[t][s]*V[s][m]) / denom[t]
//   denom[t] = sum_d Q[t][d]*Zprev[d] + rowsum(A)[t] + eps
// Q,K stored transposed in LDS (stride 68) so column reads are float4.
// A (transposed: At[s][t]) reuses K's LDS after a barrier. 66.5 KB -> 2 blk/CU.
// ---------------------------------------------------------------------------
__global__ __launch_bounds__(256) void chunkout_kernel(
    const float* __restrict__ Q, const float* __restrict__ K,
    const float* __restrict__ V,
    const float* __restrict__ Sx, const float* __restrict__ Zx,
    float* __restrict__ O)
{
    const int tid = threadIdx.x;
    const int c  = blockIdx.x % NCHUNK;
    const int bh = blockIdx.x / NCHUNK;
    const int b = bh / NHEADS, h = bh % NHEADS;

    __shared__ float Qt[DHEAD][CHUNK + 4];    // Qt[d][t]
    __shared__ float KtAt[DHEAD][CHUNK + 4];  // first Kt[d][s], later At[s][t]
    __shared__ float Vs[CHUNK][DHEAD];        // Vs[s][m]
    __shared__ float Ss[DHEAD][DHEAD];        // Sprev[d][m]
    __shared__ float zsh[DHEAD];
    __shared__ float dnm[CHUNK];

    const size_t gbase = ((size_t)(b * TSEQ + c * CHUNK)) * D_MODEL + h * DHEAD;
    const size_t sbase = (size_t)blockIdx.x * (DHEAD * DHEAD);
#pragma unroll
    for (int i = 0; i < 16; ++i) {
        const int idx = i * 256 + tid;
        const int t = idx >> 6, d = idx & 63;
        Qt[d][t]   = Q[gbase + (size_t)t * D_MODEL + d];
        KtAt[d][t] = K[gbase + (size_t)t * D_MODEL + d];
        Vs[t][d]   = V[gbase + (size_t)t * D_MODEL + d];
        Ss[t][d]   = Sx[sbase + idx];   // here t indexes the d-dim of S
    }
    if (tid < DHEAD) zsh[tid] = Zx[((size_t)bh * NCHUNK + c) * DHEAD + tid];
    __syncthreads();

    const int ty = tid >> 4, tx = tid & 15;
    const int t0 = ty * 4, s0 = tx * 4;

    // A tile: a_j components i -> A[t0+i][s0+j]
    float4 a0 = {0,0,0,0}, a1 = a0, a2 = a0, a3 = a0;
    for (int d = 0; d < DHEAD; ++d) {
        const float4 q4 = *reinterpret_cast<const float4*>(&Qt[d][t0]);
        const float4 k4 = *reinterpret_cast<const float4*>(&KtAt[d][s0]);
        fma4(a0, k4.x, q4);
        fma4(a1, k4.y, q4);
        fma4(a2, k4.z, q4);
        fma4(a3, k4.w, q4);
    }
    mask4(a0, s0 + 0, t0);
    mask4(a1, s0 + 1, t0);
    mask4(a2, s0 + 2, t0);
    mask4(a3, s0 + 3, t0);
    __syncthreads();   // all Kt reads complete before overwrite
    *reinterpret_cast<float4*>(&KtAt[s0 + 0][t0]) = a0;
    *reinterpret_cast<float4*>(&KtAt[s0 + 1][t0]) = a1;
    *reinterpret_cast<float4*>(&KtAt[s0 + 2][t0]) = a2;
    *reinterpret_cast<float4*>(&KtAt[s0 + 3][t0]) = a3;
    __syncthreads();

    if (tid < CHUNK) {
        float dv = 0.f;
        for (int s = 0; s < CHUNK; ++s) dv += KtAt[s][tid];           // rowsum(A)
        for (int d = 0; d < DHEAD; ++d) dv = fmaf(Qt[d][tid], zsh[d], dv);
        dnm[tid] = dv + EPSV;
    }
    __syncthreads();

    const int m0 = tx * 4;
    float4 o0 = {0,0,0,0}, o1 = o0, o2 = o0, o3 = o0;   // o_i over m; i is t
    for (int d = 0; d < DHEAD; ++d) {
        const float4 q4 = *reinterpret_cast<const float4*>(&Qt[d][t0]);
        const float4 s4 = *reinterpret_cast<const float4*>(&Ss[d][m0]);
        fma4(o0, q4.x, s4);
        fma4(o1, q4.y, s4);
        fma4(o2, q4.z, s4);
        fma4(o3, q4.w, s4);
    }
    for (int s = 0; s < CHUNK; ++s) {
        const float4 a4 = *reinterpret_cast<const float4*>(&KtAt[s][t0]);
        const float4 v4 = *reinterpret_cast<const float4*>(&Vs[s][m0]);
        fma4(o0, a4.x, v4);
        fma4(o1, a4.y, v4);
        fma4(o2, a4.z, v4);
        fma4(o3, a4.w, v4);
    }
    const float r0 = 1.f / dnm[t0 + 0];
    const float r1 = 1.f / dnm[t0 + 1];
    const float r2 = 1.f / dnm[t0 + 2];
    const float r3 = 1.f / dnm[t0 + 3];
    o0.x *= r0; o0.y *= r0; o0.z *= r0; o0.w *= r0;
    o1.x *= r1; o1.y *= r1; o1.z *= r1; o1.w *= r1;
    o2.x *= r2; o2.y *= r2; o2.z *= r2; o2.w *= r2;
    o3.x *= r3; o3.y *= r3; o3.z *= r3; o3.w *= r3;
    *reinterpret_cast<float4*>(&O[gbase + (size_t)(t0 + 0) * D_MODEL + m0]) = o0;
    *reinterpret_cast<float4*>(&O[gbase + (size_t)(t0 + 1) * D_MODEL + m0]) = o1;
    *reinterpret_cast<float4*>(&O[gbase + (size_t)(t0 + 2) * D_MODEL + m0]) = o2;
    *reinterpret_cast<float4*>(&O[gbase + (size_t)(t0 + 3) * D_MODEL + m0]) = o3;
}

// ---------------------------------------------------------------------------
// Kernel 5: out = O @ Wo + bo
// ---------------------------------------------------------------------------
__global__ __launch_bounds__(256) void ogemm_kernel(
    const float* __restrict__ O, const float* __restrict__ Wo,
    const float* __restrict__ bo, float* __restrict__ out)
{
    const int tid = threadIdx.x;
    const int row0 = blockIdx.x * ROWS;
    float acc[ROWS];
    const float bv = bo[tid];
#pragma unroll
    for (int r = 0; r < ROWS; ++r) acc[r] = bv;
    const float* orow = O + (size_t)row0 * D_MODEL;
    for (int k = 0; k < D_MODEL; ++k) {
        const float w = Wo[k * D_MODEL + tid];
#pragma unroll
        for (int r = 0; r < ROWS; ++r)
            acc[r] = fmaf(orow[r * D_MODEL + k], w, acc[r]);
    }
#pragma unroll
    for (int r = 0; r < ROWS; ++r)
        out[(size_t)(row0 + r) * D_MODEL + tid] = acc[r];
}

extern "C" void kernel_launch(void* const* d_in, const int* in_sizes, int n_in,
                              void* d_out, int out_size, void* d_ws, size_t ws_size,
                              hipStream_t stream)
{
    const float* x  = (const float*)d_in[0];
    const float* Wq = (const float*)d_in[1];
    const float* bq = (const float*)d_in[2];
    const float* Wk = (const float*)d_in[3];
    const float* bk = (const float*)d_in[4];
    const float* Wv = (const float*)d_in[5];
    const float* bv = (const float*)d_in[6];
    const float* Wo = (const float*)d_in[7];
    const float* bo = (const float*)d_in[8];
    float* out = (float*)d_out;

    float* Q  = (float*)d_ws;                               // 8192*256
    float* K  = Q  + (size_t)NTOK * D_MODEL;                // 8192*256
    float* V  = K  + (size_t)NTOK * D_MODEL;                // 8192*256
    float* O  = V  + (size_t)NTOK * D_MODEL;                // 8192*256
    float* KV = O  + (size_t)NTOK * D_MODEL;                // 16*32*4096
    float* Z  = KV + (size_t)NBH * NCHUNK * DHEAD * DHEAD;  // 16*32*64

    qkv_kernel<<<NTOK / ROWS, 256, 0, stream>>>(x, Wq, bq, Wk, bk, Wv, bv, Q, K, V);
    chunksum_kernel<<<NBH * NCHUNK, 256, 0, stream>>>(K, V, KV, Z);
    prefix_kernel<<<NBH * 16 + 4, 256, 0, stream>>>(KV, Z);
    chunkout_kernel<<<NBH * NCHUNK, 256, 0, stream>>>(Q, K, V, KV, Z, O);
    ogemm_kernel<<<NTOK / ROWS, 256, 0, stream>>>(O, Wo, bo, out);
}

// Round 2
// 166.960 us; speedup vs baseline: 1.4368x; 1.4368x over previous
//
#include <hip/hip_runtime.h>

#define D_MODEL 256
#define NHEADS 4
#define DHEAD 64
#define BATCH 4
#define TSEQ 2048
#define CHUNK 64
#define NCHUNK (TSEQ / CHUNK)   // 32
#define NTOK (BATCH * TSEQ)     // 8192
#define NBH (BATCH * NHEADS)    // 16
#define EPSV 1e-6f

// elu(a) + 1  ==  a+1 (a>0)  else exp(a)
__device__ __forceinline__ float elu1(float a) {
    return a > 0.0f ? a + 1.0f : __expf(a);
}

__device__ __forceinline__ void fma4(float4& o, float a, const float4& v) {
    o.x = fmaf(a, v.x, o.x);
    o.y = fmaf(a, v.y, o.y);
    o.z = fmaf(a, v.z, o.z);
    o.w = fmaf(a, v.w, o.w);
}

// zero components i of a (A[t0+i][s]) where s > t0+i (causal mask)
__device__ __forceinline__ void mask4(float4& a, int s, int t0) {
    if (s > t0 + 0) a.x = 0.f;
    if (s > t0 + 1) a.y = 0.f;
    if (s > t0 + 2) a.z = 0.f;
    if (s > t0 + 3) a.w = 0.f;
}

// ---------------------------------------------------------------------------
// Tiled fp32 GEMM tile: Out[mrow0:+64][ncol0:+64] = A[mrow0:+64][:] @ W + bias
// A is Mx256 row-major, W is 256x256 row-major. BK=32, 4x4 per thread.
// As staged transposed (As[k][row], stride 68: 16B-aligned, conflict-free
// float4 reads). Per k: 2x ds_read_b128 + 16 FMA.
// ---------------------------------------------------------------------------
__device__ __forceinline__ void gemm_tile_64(
    const float* __restrict__ A, const float* __restrict__ W,
    const float* __restrict__ bias, float* __restrict__ Out,
    int mrow0, int ncol0, int act)
{
    __shared__ float As[32][68];
    __shared__ float Bs[32][68];
    const int tid = threadIdx.x;
    const int tx = tid & 15, ty = tid >> 4;
    const int r0 = ty * 4, c0 = tx * 4;
    float4 acc0 = {0,0,0,0}, acc1 = acc0, acc2 = acc0, acc3 = acc0;

    for (int k0 = 0; k0 < 256; k0 += 32) {
        // stage A tile: 64 rows x 32 k, transposed into LDS
#pragma unroll
        for (int i = 0; i < 2; ++i) {
            const int idx = i * 256 + tid;    // 0..511
            const int row = idx >> 3;         // 0..63
            const int kq  = idx & 7;          // 0..7 (float4 index)
            const float4 v = *reinterpret_cast<const float4*>(
                &A[(size_t)(mrow0 + row) * D_MODEL + k0 + kq * 4]);
            As[kq * 4 + 0][row] = v.x;
            As[kq * 4 + 1][row] = v.y;
            As[kq * 4 + 2][row] = v.z;
            As[kq * 4 + 3][row] = v.w;
        }
        // stage B tile: 32 k x 64 cols, direct float4
#pragma unroll
        for (int i = 0; i < 2; ++i) {
            const int idx = i * 256 + tid;
            const int kr = idx >> 4;          // 0..31
            const int cq = idx & 15;          // 0..15
            const float4 v = *reinterpret_cast<const float4*>(
                &W[(size_t)(k0 + kr) * D_MODEL + ncol0 + cq * 4]);
            *reinterpret_cast<float4*>(&Bs[kr][cq * 4]) = v;
        }
        __syncthreads();
#pragma unroll
        for (int k = 0; k < 32; ++k) {
            const float4 a4 = *reinterpret_cast<const float4*>(&As[k][r0]);
            const float4 b4 = *reinterpret_cast<const float4*>(&Bs[k][c0]);
            fma4(acc0, a4.x, b4);
            fma4(acc1, a4.y, b4);
            fma4(acc2, a4.z, b4);
            fma4(acc3, a4.w, b4);
        }
        __syncthreads();
    }

    const float4 bb = *reinterpret_cast<const float4*>(&bias[ncol0 + c0]);
    float4 res[4] = {acc0, acc1, acc2, acc3};
#pragma unroll
    for (int i = 0; i < 4; ++i) {
        res[i].x += bb.x; res[i].y += bb.y; res[i].z += bb.z; res[i].w += bb.w;
        if (act) {
            res[i].x = elu1(res[i].x);
            res[i].y = elu1(res[i].y);
            res[i].z = elu1(res[i].z);
            res[i].w = elu1(res[i].w);
        }
        *reinterpret_cast<float4*>(
            &Out[(size_t)(mrow0 + r0 + i) * D_MODEL + ncol0 + c0]) = res[i];
    }
}

// ---------------------------------------------------------------------------
// Kernel 1: Q = elu1(x@Wq+bq), K = elu1(x@Wk+bk), V = x@Wv+bv
// Grid: (NTOK/64) * 12; n-tile selects {Wq,Wk,Wv} x 4 column blocks.
// n fastest so the 12 blocks sharing an A-row-tile are co-scheduled (L2).
// ---------------------------------------------------------------------------
__global__ __launch_bounds__(256) void qkv_gemm_kernel(
    const float* __restrict__ x,
    const float* __restrict__ Wq, const float* __restrict__ bq,
    const float* __restrict__ Wk, const float* __restrict__ bk,
    const float* __restrict__ Wv, const float* __restrict__ bv,
    float* __restrict__ Q, float* __restrict__ K, float* __restrict__ V)
{
    const int nblk = blockIdx.x % 12;
    const int mrow0 = (blockIdx.x / 12) * 64;
    const int which = nblk >> 2;            // 0=Q, 1=K, 2=V
    const int ncol0 = (nblk & 3) * 64;
    const float* W    = (which == 0) ? Wq : (which == 1) ? Wk : Wv;
    const float* bias = (which == 0) ? bq : (which == 1) ? bk : bv;
    float* Out        = (which == 0) ? Q  : (which == 1) ? K  : V;
    gemm_tile_64(x, W, bias, Out, mrow0, ncol0, which < 2 ? 1 : 0);
}

// ---------------------------------------------------------------------------
// Kernel 5: out = O @ Wo + bo  (same tile)
// ---------------------------------------------------------------------------
__global__ __launch_bounds__(256) void ogemm_kernel(
    const float* __restrict__ O, const float* __restrict__ Wo,
    const float* __restrict__ bo, float* __restrict__ out)
{
    const int ncol0 = (blockIdx.x & 3) * 64;
    const int mrow0 = (blockIdx.x >> 2) * 64;
    gemm_tile_64(O, Wo, bo, out, mrow0, ncol0, 0);
}

// ---------------------------------------------------------------------------
// Kernel 2: per-chunk KV_c[d][m] = sum_t K[t][d]*V[t][m]   (64x64)
//           Z_c[d]   = sum_t K[t][d]
// ---------------------------------------------------------------------------
__global__ __launch_bounds__(256) void chunksum_kernel(
    const float* __restrict__ K, const float* __restrict__ V,
    float* __restrict__ KVc, float* __restrict__ Zc)
{
    const int tid = threadIdx.x;
    const int c  = blockIdx.x % NCHUNK;
    const int bh = blockIdx.x / NCHUNK;
    const int b = bh / NHEADS, h = bh % NHEADS;

    __shared__ float Ks[CHUNK][DHEAD + 4];
    __shared__ float Vs[CHUNK][DHEAD];

    const size_t gbase = ((size_t)(b * TSEQ + c * CHUNK)) * D_MODEL + h * DHEAD;
#pragma unroll
    for (int i = 0; i < 16; ++i) {
        const int idx = i * 256 + tid;
        const int t = idx >> 6, d = idx & 63;
        Ks[t][d] = K[gbase + (size_t)t * D_MODEL + d];
        Vs[t][d] = V[gbase + (size_t)t * D_MODEL + d];
    }
    __syncthreads();

    const int ty = tid >> 4, tx = tid & 15;
    const int d0 = ty * 4, m0 = tx * 4;
    float4 o0 = {0,0,0,0}, o1 = o0, o2 = o0, o3 = o0;
    for (int t = 0; t < CHUNK; ++t) {
        const float4 k4 = *reinterpret_cast<const float4*>(&Ks[t][d0]);
        const float4 v4 = *reinterpret_cast<const float4*>(&Vs[t][m0]);
        fma4(o0, k4.x, v4);
        fma4(o1, k4.y, v4);
        fma4(o2, k4.z, v4);
        fma4(o3, k4.w, v4);
    }
    float* kvb = KVc + (size_t)blockIdx.x * (DHEAD * DHEAD);
    *reinterpret_cast<float4*>(&kvb[(d0 + 0) * DHEAD + m0]) = o0;
    *reinterpret_cast<float4*>(&kvb[(d0 + 1) * DHEAD + m0]) = o1;
    *reinterpret_cast<float4*>(&kvb[(d0 + 2) * DHEAD + m0]) = o2;
    *reinterpret_cast<float4*>(&kvb[(d0 + 3) * DHEAD + m0]) = o3;

    if (tid < DHEAD) {
        float z = 0.f;
        for (int t = 0; t < CHUNK; ++t) z += Ks[t][tid];
        Zc[(size_t)blockIdx.x * DHEAD + tid] = z;
    }
}

// ---------------------------------------------------------------------------
// Kernel 3: in-place EXCLUSIVE prefix sum over chunks, per (b,h), per element.
// ---------------------------------------------------------------------------
__global__ __launch_bounds__(256) void prefix_kernel(
    float* __restrict__ KVc, float* __restrict__ Zc)
{
    const int tid = threadIdx.x;
    if (blockIdx.x < NBH * 16) {
        const int bh = blockIdx.x >> 4;
        const int e = ((blockIdx.x & 15) << 8) + tid;   // 0..4095
        float s = 0.f;
        for (int c = 0; c < NCHUNK; ++c) {
            const size_t idx = ((size_t)(bh * NCHUNK + c)) * (DHEAD * DHEAD) + e;
            const float v = KVc[idx];
            KVc[idx] = s;
            s += v;
        }
    } else {
        const int j = ((int)(blockIdx.x - NBH * 16) << 8) + tid;  // 0..1023
        if (j < NBH * DHEAD) {
            const int bh = j >> 6, d = j & 63;
            float s = 0.f;
            for (int c = 0; c < NCHUNK; ++c) {
                const int idx = (bh * NCHUNK + c) * DHEAD + d;
                const float v = Zc[idx];
                Zc[idx] = s;
                s += v;
            }
        }
    }
}

// ---------------------------------------------------------------------------
// Kernel 4: per-chunk output.
//   A = tril(Q K^T); O = (Q Sprev + A V) / (Q.Zprev + rowsum(A) + eps)
// ---------------------------------------------------------------------------
__global__ __launch_bounds__(256) void chunkout_kernel(
    const float* __restrict__ Q, const float* __restrict__ K,
    const float* __restrict__ V,
    const float* __restrict__ Sx, const float* __restrict__ Zx,
    float* __restrict__ O)
{
    const int tid = threadIdx.x;
    const int c  = blockIdx.x % NCHUNK;
    const int bh = blockIdx.x / NCHUNK;
    const int b = bh / NHEADS, h = bh % NHEADS;

    __shared__ float Qt[DHEAD][CHUNK + 4];    // Qt[d][t]
    __shared__ float KtAt[DHEAD][CHUNK + 4];  // first Kt[d][s], later At[s][t]
    __shared__ float Vs[CHUNK][DHEAD];        // Vs[s][m]
    __shared__ float Ss[DHEAD][DHEAD];        // Sprev[d][m]
    __shared__ float zsh[DHEAD];
    __shared__ float dnm[CHUNK];

    const size_t gbase = ((size_t)(b * TSEQ + c * CHUNK)) * D_MODEL + h * DHEAD;
    const size_t sbase = (size_t)blockIdx.x * (DHEAD * DHEAD);
#pragma unroll
    for (int i = 0; i < 16; ++i) {
        const int idx = i * 256 + tid;
        const int t = idx >> 6, d = idx & 63;
        Qt[d][t]   = Q[gbase + (size_t)t * D_MODEL + d];
        KtAt[d][t] = K[gbase + (size_t)t * D_MODEL + d];
        Vs[t][d]   = V[gbase + (size_t)t * D_MODEL + d];
        Ss[t][d]   = Sx[sbase + idx];
    }
    if (tid < DHEAD) zsh[tid] = Zx[((size_t)bh * NCHUNK + c) * DHEAD + tid];
    __syncthreads();

    const int ty = tid >> 4, tx = tid & 15;
    const int t0 = ty * 4, s0 = tx * 4;

    float4 a0 = {0,0,0,0}, a1 = a0, a2 = a0, a3 = a0;
    for (int d = 0; d < DHEAD; ++d) {
        const float4 q4 = *reinterpret_cast<const float4*>(&Qt[d][t0]);
        const float4 k4 = *reinterpret_cast<const float4*>(&KtAt[d][s0]);
        fma4(a0, k4.x, q4);
        fma4(a1, k4.y, q4);
        fma4(a2, k4.z, q4);
        fma4(a3, k4.w, q4);
    }
    mask4(a0, s0 + 0, t0);
    mask4(a1, s0 + 1, t0);
    mask4(a2, s0 + 2, t0);
    mask4(a3, s0 + 3, t0);
    __syncthreads();
    *reinterpret_cast<float4*>(&KtAt[s0 + 0][t0]) = a0;
    *reinterpret_cast<float4*>(&KtAt[s0 + 1][t0]) = a1;
    *reinterpret_cast<float4*>(&KtAt[s0 + 2][t0]) = a2;
    *reinterpret_cast<float4*>(&KtAt[s0 + 3][t0]) = a3;
    __syncthreads();

    if (tid < CHUNK) {
        float dv = 0.f;
        for (int s = 0; s < CHUNK; ++s) dv += KtAt[s][tid];
        for (int d = 0; d < DHEAD; ++d) dv = fmaf(Qt[d][tid], zsh[d], dv);
        dnm[tid] = dv + EPSV;
    }
    __syncthreads();

    const int m0 = tx * 4;
    float4 o0 = {0,0,0,0}, o1 = o0, o2 = o0, o3 = o0;
    for (int d = 0; d < DHEAD; ++d) {
        const float4 q4 = *reinterpret_cast<const float4*>(&Qt[d][t0]);
        const float4 s4 = *reinterpret_cast<const float4*>(&Ss[d][m0]);
        fma4(o0, q4.x, s4);
        fma4(o1, q4.y, s4);
        fma4(o2, q4.z, s4);
        fma4(o3, q4.w, s4);
    }
    for (int s = 0; s < CHUNK; ++s) {
        const float4 a4 = *reinterpret_cast<const float4*>(&KtAt[s][t0]);
        const float4 v4 = *reinterpret_cast<const float4*>(&Vs[s][m0]);
        fma4(o0, a4.x, v4);
        fma4(o1, a4.y, v4);
        fma4(o2, a4.z, v4);
        fma4(o3, a4.w, v4);
    }
    const float r0 = 1.f / dnm[t0 + 0];
    const float r1 = 1.f / dnm[t0 + 1];
    const float r2 = 1.f / dnm[t0 + 2];
    const float r3 = 1.f / dnm[t0 + 3];
    o0.x *= r0; o0.y *= r0; o0.z *= r0; o0.w *= r0;
    o1.x *= r1; o1.y *= r1; o1.z *= r1; o1.w *= r1;
    o2.x *= r2; o2.y *= r2; o2.z *= r2; o2.w *= r2;
    o3.x *= r3; o3.y *= r3; o3.z *= r3; o3.w *= r3;
    *reinterpret_cast<float4*>(&O[gbase + (size_t)(t0 + 0) * D_MODEL + m0]) = o0;
    *reinterpret_cast<float4*>(&O[gbase + (size_t)(t0 + 1) * D_MODEL + m0]) = o1;
    *reinterpret_cast<float4*>(&O[gbase + (size_t)(t0 + 2) * D_MODEL + m0]) = o2;
    *reinterpret_cast<float4*>(&O[gbase + (size_t)(t0 + 3) * D_MODEL + m0]) = o3;
}

extern "C" void kernel_launch(void* const* d_in, const int* in_sizes, int n_in,
                              void* d_out, int out_size, void* d_ws, size_t ws_size,
                              hipStream_t stream)
{
    const float* x  = (const float*)d_in[0];
    const float* Wq = (const float*)d_in[1];
    const float* bq = (const float*)d_in[2];
    const float* Wk = (const float*)d_in[3];
    const float* bk = (const float*)d_in[4];
    const float* Wv = (const float*)d_in[5];
    const float* bv = (const float*)d_in[6];
    const float* Wo = (const float*)d_in[7];
    const float* bo = (const float*)d_in[8];
    float* out = (float*)d_out;

    float* Q  = (float*)d_ws;                               // 8192*256
    float* K  = Q  + (size_t)NTOK * D_MODEL;
    float* V  = K  + (size_t)NTOK * D_MODEL;
    float* O  = V  + (size_t)NTOK * D_MODEL;
    float* KV = O  + (size_t)NTOK * D_MODEL;                // 16*32*4096
    float* Z  = KV + (size_t)NBH * NCHUNK * DHEAD * DHEAD;  // 16*32*64

    qkv_gemm_kernel<<<(NTOK / 64) * 12, 256, 0, stream>>>(
        x, Wq, bq, Wk, bk, Wv, bv, Q, K, V);
    chunksum_kernel<<<NBH * NCHUNK, 256, 0, stream>>>(K, V, KV, Z);
    prefix_kernel<<<NBH * 16 + 4, 256, 0, stream>>>(KV, Z);
    chunkout_kernel<<<NBH * NCHUNK, 256, 0, stream>>>(Q, K, V, KV, Z, O);
    ogemm_kernel<<<(NTOK / 64) * 4, 256, 0, stream>>>(O, Wo, bo, out);
}

// Round 3
// 124.893 us; speedup vs baseline: 1.9207x; 1.3368x over previous
//
#include <hip/hip_runtime.h>
#include <hip/hip_bf16.h>

#define D_MODEL 256
#define NHEADS 4
#define DHEAD 64
#define BATCH 4
#define TSEQ 2048
#define CHUNK 64
#define NCHUNK (TSEQ / CHUNK)   // 32
#define NTOK (BATCH * TSEQ)     // 8192
#define NBH (BATCH * NHEADS)    // 16
#define EPSV 1e-6f

typedef __bf16 bf16x8 __attribute__((ext_vector_type(8)));
typedef float f32x4 __attribute__((ext_vector_type(4)));

// elu(a) + 1  ==  a+1 (a>0)  else exp(a)
__device__ __forceinline__ float elu1(float a) {
    return a > 0.0f ? a + 1.0f : __expf(a);
}

__device__ __forceinline__ unsigned short f2bf(float f) {
    __hip_bfloat16 h = __float2bfloat16(f);   // RNE
    return __builtin_bit_cast(unsigned short, h);
}

__device__ __forceinline__ void fma4(float4& o, float a, const float4& v) {
    o.x = fmaf(a, v.x, o.x);
    o.y = fmaf(a, v.y, o.y);
    o.z = fmaf(a, v.z, o.z);
    o.w = fmaf(a, v.w, o.w);
}

__device__ __forceinline__ void mask4(float4& a, int s, int t0) {
    if (s > t0 + 0) a.x = 0.f;
    if (s > t0 + 1) a.y = 0.f;
    if (s > t0 + 2) a.z = 0.f;
    if (s > t0 + 3) a.w = 0.f;
}

// async global->LDS, 16B per lane; lds ptr must be wave-uniform base.
__device__ __forceinline__ void gld_lds16(const void* g, void* l) {
    __builtin_amdgcn_global_load_lds(
        (const __attribute__((address_space(1))) void*)g,
        (__attribute__((address_space(3))) void*)l, 16, 0, 0);
}

// ---------------------------------------------------------------------------
// convert x (fp32) -> xb (bf16)
// ---------------------------------------------------------------------------
__global__ __launch_bounds__(256) void convert_x_kernel(
    const float* __restrict__ x, unsigned short* __restrict__ xb)
{
    const int i = (blockIdx.x * 256 + threadIdx.x) * 8;
    const float4 a = *reinterpret_cast<const float4*>(&x[i]);
    const float4 b = *reinterpret_cast<const float4*>(&x[i + 4]);
    ushort4 u0 = { f2bf(a.x), f2bf(a.y), f2bf(a.z), f2bf(a.w) };
    ushort4 u1 = { f2bf(b.x), f2bf(b.y), f2bf(b.z), f2bf(b.w) };
    *reinterpret_cast<ushort4*>(&xb[i]) = u0;
    *reinterpret_cast<ushort4*>(&xb[i + 4]) = u1;
}

// ---------------------------------------------------------------------------
// transpose-convert W[k][n] fp32 -> Wt[n][k] bf16.
// Wq,Wk,Wv -> Wt rows [0,768); Wo -> Wot rows [0,256).
// 64 blocks: 4 matrices x 16 (64x64) tiles.
// ---------------------------------------------------------------------------
__global__ __launch_bounds__(256) void convert_w_kernel(
    const float* __restrict__ Wq, const float* __restrict__ Wk,
    const float* __restrict__ Wv, const float* __restrict__ Wo,
    unsigned short* __restrict__ Wt, unsigned short* __restrict__ Wot)
{
    __shared__ float Ls[64][65];
    const int tid = threadIdx.x;
    const int wi = blockIdx.x >> 4;          // 0..3
    const int ti = blockIdx.x & 15;
    const int k0 = (ti >> 2) * 64, n0 = (ti & 3) * 64;
    const float* W = wi == 0 ? Wq : wi == 1 ? Wk : wi == 2 ? Wv : Wo;
#pragma unroll
    for (int i = 0; i < 16; ++i) {
        const int idx = i * 256 + tid;
        const int r = idx >> 6, c = idx & 63;
        Ls[r][c] = W[(size_t)(k0 + r) * D_MODEL + n0 + c];
    }
    __syncthreads();
    unsigned short* outp = (wi < 3) ? (Wt + (size_t)(wi * 256 + n0) * D_MODEL + k0)
                                    : (Wot + (size_t)n0 * D_MODEL + k0);
#pragma unroll
    for (int i = 0; i < 16; ++i) {
        const int idx = i * 256 + tid;
        const int rn = idx >> 6, ck = idx & 63;
        outp[(size_t)rn * D_MODEL + ck] = f2bf(Ls[ck][rn]);
    }
}

// ---------------------------------------------------------------------------
// MFMA bf16 GEMM: Out[m][n] = A[m][:] @ B + bias, B given transposed
// (Bt[n][k]). 128x128 tile, BK=64, 4 waves x 4x4 of mfma_f32_16x16x32_bf16.
// global_load_lds(16B) staging; LDS chunk-XOR swizzle: slot (m,s) holds
// global 16B-chunk s^(m&7) so frag reads spread across all 32 banks.
// MODE 0: qkv (Bt has 768 rows; n-tile selects Q/K/V, elu1 on Q,K).
// MODE 1: plain (Bt 256 rows, out = O0 + bias).
// Outputs fp32.
// ---------------------------------------------------------------------------
template<int MODE>
__global__ __launch_bounds__(256) void mfma_gemm_kernel(
    const unsigned short* __restrict__ A,
    const unsigned short* __restrict__ Bt,
    const float* __restrict__ b0, const float* __restrict__ b1,
    const float* __restrict__ b2,
    float* __restrict__ O0, float* __restrict__ O1, float* __restrict__ O2)
{
    __shared__ __align__(16) unsigned short As[128 * 64];
    __shared__ __align__(16) unsigned short Bs[128 * 64];
    const int tid = threadIdx.x;
    const int wave = tid >> 6, lane = tid & 63;
    const int la = lane & 15, q = lane >> 4;
    const int wm = (wave >> 1) * 64, wn = (wave & 1) * 64;

    int mtile, ntile;
    if (MODE == 0) { ntile = blockIdx.x % 6; mtile = blockIdx.x / 6; }
    else           { ntile = blockIdx.x & 1; mtile = blockIdx.x >> 1; }
    const int m0 = mtile * 128, n0 = ntile * 128;

    const unsigned short* Ab = A  + (size_t)m0 * D_MODEL;
    const unsigned short* Bb = Bt + (size_t)n0 * D_MODEL;

    f32x4 acc[4][4];
#pragma unroll
    for (int i = 0; i < 4; ++i)
#pragma unroll
        for (int j = 0; j < 4; ++j) acc[i][j] = (f32x4){0.f, 0.f, 0.f, 0.f};

    for (int k0 = 0; k0 < D_MODEL; k0 += 64) {
#pragma unroll
        for (int i = 0; i < 4; ++i) {
            const int bslot = i * 256 + wave * 64;   // wave-uniform
            const int slot = bslot + lane;
            const int m = slot >> 3, s = slot & 7;
            const int g = s ^ (m & 7);
            gld_lds16(Ab + (size_t)m * D_MODEL + k0 + g * 8, &As[bslot * 8]);
            gld_lds16(Bb + (size_t)m * D_MODEL + k0 + g * 8, &Bs[bslot * 8]);
        }
        __syncthreads();   // compiler emits vmcnt(0) drain before barrier

        bf16x8 af[4][2], bfr[4][2];
#pragma unroll
        for (int i = 0; i < 4; ++i) {
#pragma unroll
            for (int kh = 0; kh < 2; ++kh) {
                const int g = kh * 4 + q;            // 16B-chunk index within row
                const int m = wm + i * 16 + la;
                af[i][kh] = *reinterpret_cast<const bf16x8*>(
                    &As[m * 64 + ((g ^ (m & 7)) << 3)]);
                const int n = wn + i * 16 + la;
                bfr[i][kh] = *reinterpret_cast<const bf16x8*>(
                    &Bs[n * 64 + ((g ^ (n & 7)) << 3)]);
            }
        }
#pragma unroll
        for (int mi = 0; mi < 4; ++mi)
#pragma unroll
            for (int ni = 0; ni < 4; ++ni) {
                acc[mi][ni] = __builtin_amdgcn_mfma_f32_16x16x32_bf16(
                    af[mi][0], bfr[ni][0], acc[mi][ni], 0, 0, 0);
                acc[mi][ni] = __builtin_amdgcn_mfma_f32_16x16x32_bf16(
                    af[mi][1], bfr[ni][1], acc[mi][ni], 0, 0, 0);
            }
        __syncthreads();
    }

    // epilogue: C/D layout col=lane&15, row=(lane>>4)*4+reg  [m89/m91]
#pragma unroll
    for (int mi = 0; mi < 4; ++mi) {
#pragma unroll
        for (int ni = 0; ni < 4; ++ni) {
            const int row = m0 + wm + mi * 16 + q * 4;
            const int col = n0 + wn + ni * 16 + la;
            float* Out; const float* bias; int act, cl;
            if (MODE == 0) {
                const int which = col >> 8;          // block-uniform
                cl = col & 255;
                Out  = which == 0 ? O0 : which == 1 ? O1 : O2;
                bias = which == 0 ? b0 : which == 1 ? b1 : b2;
                act = (which < 2);
            } else { Out = O0; bias = b0; act = 0; cl = col; }
            const float bv = bias[cl];
#pragma unroll
            for (int r = 0; r < 4; ++r) {
                float v = acc[mi][ni][r] + bv;
                if (act) v = elu1(v);
                Out[(size_t)(row + r) * D_MODEL + cl] = v;
            }
        }
    }
}

// ---------------------------------------------------------------------------
// Kernel 2: per-chunk KV_c[d][m] = sum_t K[t][d]*V[t][m]; Z_c[d] = sum_t K[t][d]
// ---------------------------------------------------------------------------
__global__ __launch_bounds__(256) void chunksum_kernel(
    const float* __restrict__ K, const float* __restrict__ V,
    float* __restrict__ KVc, float* __restrict__ Zc)
{
    const int tid = threadIdx.x;
    const int c  = blockIdx.x % NCHUNK;
    const int bh = blockIdx.x / NCHUNK;
    const int b = bh / NHEADS, h = bh % NHEADS;

    __shared__ float Ks[CHUNK][DHEAD + 4];
    __shared__ float Vs[CHUNK][DHEAD];

    const size_t gbase = ((size_t)(b * TSEQ + c * CHUNK)) * D_MODEL + h * DHEAD;
#pragma unroll
    for (int i = 0; i < 16; ++i) {
        const int idx = i * 256 + tid;
        const int t = idx >> 6, d = idx & 63;
        Ks[t][d] = K[gbase + (size_t)t * D_MODEL + d];
        Vs[t][d] = V[gbase + (size_t)t * D_MODEL + d];
    }
    __syncthreads();

    const int ty = tid >> 4, tx = tid & 15;
    const int d0 = ty * 4, m0 = tx * 4;
    float4 o0 = {0,0,0,0}, o1 = o0, o2 = o0, o3 = o0;
    for (int t = 0; t < CHUNK; ++t) {
        const float4 k4 = *reinterpret_cast<const float4*>(&Ks[t][d0]);
        const float4 v4 = *reinterpret_cast<const float4*>(&Vs[t][m0]);
        fma4(o0, k4.x, v4);
        fma4(o1, k4.y, v4);
        fma4(o2, k4.z, v4);
        fma4(o3, k4.w, v4);
    }
    float* kvb = KVc + (size_t)blockIdx.x * (DHEAD * DHEAD);
    *reinterpret_cast<float4*>(&kvb[(d0 + 0) * DHEAD + m0]) = o0;
    *reinterpret_cast<float4*>(&kvb[(d0 + 1) * DHEAD + m0]) = o1;
    *reinterpret_cast<float4*>(&kvb[(d0 + 2) * DHEAD + m0]) = o2;
    *reinterpret_cast<float4*>(&kvb[(d0 + 3) * DHEAD + m0]) = o3;

    if (tid < DHEAD) {
        float z = 0.f;
        for (int t = 0; t < CHUNK; ++t) z += Ks[t][tid];
        Zc[(size_t)blockIdx.x * DHEAD + tid] = z;
    }
}

// ---------------------------------------------------------------------------
// Kernel 3: in-place EXCLUSIVE prefix sum over chunks, per (b,h), per element.
// ---------------------------------------------------------------------------
__global__ __launch_bounds__(256) void prefix_kernel(
    float* __restrict__ KVc, float* __restrict__ Zc)
{
    const int tid = threadIdx.x;
    if (blockIdx.x < NBH * 16) {
        const int bh = blockIdx.x >> 4;
        const int e = ((blockIdx.x & 15) << 8) + tid;
        float s = 0.f;
        for (int c = 0; c < NCHUNK; ++c) {
            const size_t idx = ((size_t)(bh * NCHUNK + c)) * (DHEAD * DHEAD) + e;
            const float v = KVc[idx];
            KVc[idx] = s;
            s += v;
        }
    } else {
        const int j = ((int)(blockIdx.x - NBH * 16) << 8) + tid;
        if (j < NBH * DHEAD) {
            const int bh = j >> 6, d = j & 63;
            float s = 0.f;
            for (int c = 0; c < NCHUNK; ++c) {
                const int idx = (bh * NCHUNK + c) * DHEAD + d;
                const float v = Zc[idx];
                Zc[idx] = s;
                s += v;
            }
        }
    }
}

// ---------------------------------------------------------------------------
// Kernel 4: per-chunk output; now emits bf16 O for the MFMA ogemm.
// ---------------------------------------------------------------------------
__global__ __launch_bounds__(256) void chunkout_kernel(
    const float* __restrict__ Q, const float* __restrict__ K,
    const float* __restrict__ V,
    const float* __restrict__ Sx, const float* __restrict__ Zx,
    unsigned short* __restrict__ Ob)
{
    const int tid = threadIdx.x;
    const int c  = blockIdx.x % NCHUNK;
    const int bh = blockIdx.x / NCHUNK;
    const int b = bh / NHEADS, h = bh % NHEADS;

    __shared__ float Qt[DHEAD][CHUNK + 4];    // Qt[d][t]
    __shared__ float KtAt[DHEAD][CHUNK + 4];  // first Kt[d][s], later At[s][t]
    __shared__ float Vs[CHUNK][DHEAD];
    __shared__ float Ss[DHEAD][DHEAD];
    __shared__ float zsh[DHEAD];
    __shared__ float dnm[CHUNK];

    const size_t gbase = ((size_t)(b * TSEQ + c * CHUNK)) * D_MODEL + h * DHEAD;
    const size_t sbase = (size_t)blockIdx.x * (DHEAD * DHEAD);
#pragma unroll
    for (int i = 0; i < 16; ++i) {
        const int idx = i * 256 + tid;
        const int t = idx >> 6, d = idx & 63;
        Qt[d][t]   = Q[gbase + (size_t)t * D_MODEL + d];
        KtAt[d][t] = K[gbase + (size_t)t * D_MODEL + d];
        Vs[t][d]   = V[gbase + (size_t)t * D_MODEL + d];
        Ss[t][d]   = Sx[sbase + idx];
    }
    if (tid < DHEAD) zsh[tid] = Zx[((size_t)bh * NCHUNK + c) * DHEAD + tid];
    __syncthreads();

    const int ty = tid >> 4, tx = tid & 15;
    const int t0 = ty * 4, s0 = tx * 4;

    float4 a0 = {0,0,0,0}, a1 = a0, a2 = a0, a3 = a0;
    for (int d = 0; d < DHEAD; ++d) {
        const float4 q4 = *reinterpret_cast<const float4*>(&Qt[d][t0]);
        const float4 k4 = *reinterpret_cast<const float4*>(&KtAt[d][s0]);
        fma4(a0, k4.x, q4);
        fma4(a1, k4.y, q4);
        fma4(a2, k4.z, q4);
        fma4(a3, k4.w, q4);
    }
    mask4(a0, s0 + 0, t0);
    mask4(a1, s0 + 1, t0);
    mask4(a2, s0 + 2, t0);
    mask4(a3, s0 + 3, t0);
    __syncthreads();
    *reinterpret_cast<float4*>(&KtAt[s0 + 0][t0]) = a0;
    *reinterpret_cast<float4*>(&KtAt[s0 + 1][t0]) = a1;
    *reinterpret_cast<float4*>(&KtAt[s0 + 2][t0]) = a2;
    *reinterpret_cast<float4*>(&KtAt[s0 + 3][t0]) = a3;
    __syncthreads();

    if (tid < CHUNK) {
        float dv = 0.f;
        for (int s = 0; s < CHUNK; ++s) dv += KtAt[s][tid];
        for (int d = 0; d < DHEAD; ++d) dv = fmaf(Qt[d][tid], zsh[d], dv);
        dnm[tid] = dv + EPSV;
    }
    __syncthreads();

    const int m0 = tx * 4;
    float4 o0 = {0,0,0,0}, o1 = o0, o2 = o0, o3 = o0;
    for (int d = 0; d < DHEAD; ++d) {
        const float4 q4 = *reinterpret_cast<const float4*>(&Qt[d][t0]);
        const float4 s4 = *reinterpret_cast<const float4*>(&Ss[d][m0]);
        fma4(o0, q4.x, s4);
        fma4(o1, q4.y, s4);
        fma4(o2, q4.z, s4);
        fma4(o3, q4.w, s4);
    }
    for (int s = 0; s < CHUNK; ++s) {
        const float4 a4 = *reinterpret_cast<const float4*>(&KtAt[s][t0]);
        const float4 v4 = *reinterpret_cast<const float4*>(&Vs[s][m0]);
        fma4(o0, a4.x, v4);
        fma4(o1, a4.y, v4);
        fma4(o2, a4.z, v4);
        fma4(o3, a4.w, v4);
    }
    const float r0 = 1.f / dnm[t0 + 0];
    const float r1 = 1.f / dnm[t0 + 1];
    const float r2 = 1.f / dnm[t0 + 2];
    const float r3 = 1.f / dnm[t0 + 3];
    ushort4 p0 = { f2bf(o0.x * r0), f2bf(o0.y * r0), f2bf(o0.z * r0), f2bf(o0.w * r0) };
    ushort4 p1 = { f2bf(o1.x * r1), f2bf(o1.y * r1), f2bf(o1.z * r1), f2bf(o1.w * r1) };
    ushort4 p2 = { f2bf(o2.x * r2), f2bf(o2.y * r2), f2bf(o2.z * r2), f2bf(o2.w * r2) };
    ushort4 p3 = { f2bf(o3.x * r3), f2bf(o3.y * r3), f2bf(o3.z * r3), f2bf(o3.w * r3) };
    *reinterpret_cast<ushort4*>(&Ob[gbase + (size_t)(t0 + 0) * D_MODEL + m0]) = p0;
    *reinterpret_cast<ushort4*>(&Ob[gbase + (size_t)(t0 + 1) * D_MODEL + m0]) = p1;
    *reinterpret_cast<ushort4*>(&Ob[gbase + (size_t)(t0 + 2) * D_MODEL + m0]) = p2;
    *reinterpret_cast<ushort4*>(&Ob[gbase + (size_t)(t0 + 3) * D_MODEL + m0]) = p3;
}

extern "C" void kernel_launch(void* const* d_in, const int* in_sizes, int n_in,
                              void* d_out, int out_size, void* d_ws, size_t ws_size,
                              hipStream_t stream)
{
    const float* x  = (const float*)d_in[0];
    const float* Wq = (const float*)d_in[1];
    const float* bq = (const float*)d_in[2];
    const float* Wk = (const float*)d_in[3];
    const float* bk = (const float*)d_in[4];
    const float* Wv = (const float*)d_in[5];
    const float* bv = (const float*)d_in[6];
    const float* Wo = (const float*)d_in[7];
    const float* bo = (const float*)d_in[8];
    float* out = (float*)d_out;

    float* Q  = (float*)d_ws;                               // 2M f32
    float* K  = Q  + (size_t)NTOK * D_MODEL;                // 2M f32
    float* V  = K  + (size_t)NTOK * D_MODEL;                // 2M f32
    float* KV = V  + (size_t)NTOK * D_MODEL;                // 2M f32
    float* Z  = KV + (size_t)NBH * NCHUNK * DHEAD * DHEAD;  // 32K f32
    unsigned short* xb  = (unsigned short*)(Z + NBH * NCHUNK * DHEAD);  // 2M bf16
    unsigned short* Ob  = xb;   // aliases xb: dead after qkv gemm
    unsigned short* Wt  = xb + (size_t)NTOK * D_MODEL;      // 768*256 bf16
    unsigned short* Wot = Wt + 768 * 256;                   // 256*256 bf16

    convert_x_kernel<<<NTOK * D_MODEL / 8 / 256, 256, 0, stream>>>(x, xb);
    convert_w_kernel<<<64, 256, 0, stream>>>(Wq, Wk, Wv, Wo, Wt, Wot);
    mfma_gemm_kernel<0><<<(NTOK / 128) * 6, 256, 0, stream>>>(
        xb, Wt, bq, bk, bv, Q, K, V);
    chunksum_kernel<<<NBH * NCHUNK, 256, 0, stream>>>(K, V, KV, Z);
    prefix_kernel<<<NBH * 16 + 4, 256, 0, stream>>>(KV, Z);
    chunkout_kernel<<<NBH * NCHUNK, 256, 0, stream>>>(Q, K, V, KV, Z, Ob);
    mfma_gemm_kernel<1><<<(NTOK / 128) * 2, 256, 0, stream>>>(
        Ob, Wot, bo, nullptr, nullptr, out, nullptr, nullptr);
}

// Round 6
// 122.925 us; speedup vs baseline: 1.9515x; 1.0160x over previous
//
#include <hip/hip_runtime.h>
#include <hip/hip_bf16.h>

#define D_MODEL 256
#define NHEADS 4
#define DHEAD 64
#define BATCH 4
#define TSEQ 2048
#define CHUNK 64
#define NCHUNK (TSEQ / CHUNK)   // 32
#define NTOK (BATCH * TSEQ)     // 8192
#define NBH (BATCH * NHEADS)    // 16
#define EPSV 1e-6f

typedef __bf16 bf16x8 __attribute__((ext_vector_type(8)));
typedef float f32x4 __attribute__((ext_vector_type(4)));

__device__ __forceinline__ float elu1(float a) {
    return a > 0.0f ? a + 1.0f : __expf(a);
}

__device__ __forceinline__ unsigned short f2bf(float f) {
    __hip_bfloat16 h = __float2bfloat16(f);   // RNE
    return __builtin_bit_cast(unsigned short, h);
}

__device__ __forceinline__ float bf2f(unsigned short u) {
    return __bfloat162float(__builtin_bit_cast(__hip_bfloat16, u));
}

__device__ __forceinline__ void fma4(float4& o, float a, const float4& v) {
    o.x = fmaf(a, v.x, o.x);
    o.y = fmaf(a, v.y, o.y);
    o.z = fmaf(a, v.z, o.z);
    o.w = fmaf(a, v.w, o.w);
}

__device__ __forceinline__ void mask4(float4& a, int s, int t0) {
    if (s > t0 + 0) a.x = 0.f;
    if (s > t0 + 1) a.y = 0.f;
    if (s > t0 + 2) a.z = 0.f;
    if (s > t0 + 3) a.w = 0.f;
}

// async global->LDS, 16B per lane; lds ptr must be wave-uniform base.
__device__ __forceinline__ void gld_lds16(const void* g, void* l) {
    __builtin_amdgcn_global_load_lds(
        (const __attribute__((address_space(1))) void*)g,
        (__attribute__((address_space(3))) void*)l, 16, 0, 0);
}

// ---------------------------------------------------------------------------
// convert x (fp32) -> xb (bf16)
// ---------------------------------------------------------------------------
__global__ __launch_bounds__(256) void convert_x_kernel(
    const float* __restrict__ x, unsigned short* __restrict__ xb)
{
    const int i = (blockIdx.x * 256 + threadIdx.x) * 8;
    const float4 a = *reinterpret_cast<const float4*>(&x[i]);
    const float4 b = *reinterpret_cast<const float4*>(&x[i + 4]);
    ushort4 u0 = { f2bf(a.x), f2bf(a.y), f2bf(a.z), f2bf(a.w) };
    ushort4 u1 = { f2bf(b.x), f2bf(b.y), f2bf(b.z), f2bf(b.w) };
    *reinterpret_cast<ushort4*>(&xb[i]) = u0;
    *reinterpret_cast<ushort4*>(&xb[i + 4]) = u1;
}

// ---------------------------------------------------------------------------
// transpose-convert W[k][n] fp32 -> Wt[n][k] bf16 (Wq,Wk,Wv -> 768 rows; Wo).
// ---------------------------------------------------------------------------
__global__ __launch_bounds__(256) void convert_w_kernel(
    const float* __restrict__ Wq, const float* __restrict__ Wk,
    const float* __restrict__ Wv, const float* __restrict__ Wo,
    unsigned short* __restrict__ Wt, unsigned short* __restrict__ Wot)
{
    __shared__ float Ls[64][65];
    const int tid = threadIdx.x;
    const int wi = blockIdx.x >> 4;
    const int ti = blockIdx.x & 15;
    const int k0 = (ti >> 2) * 64, n0 = (ti & 3) * 64;
    const float* W = wi == 0 ? Wq : wi == 1 ? Wk : wi == 2 ? Wv : Wo;
#pragma unroll
    for (int i = 0; i < 16; ++i) {
        const int idx = i * 256 + tid;
        const int r = idx >> 6, c = idx & 63;
        Ls[r][c] = W[(size_t)(k0 + r) * D_MODEL + n0 + c];
    }
    __syncthreads();
    unsigned short* outp = (wi < 3) ? (Wt + (size_t)(wi * 256 + n0) * D_MODEL + k0)
                                    : (Wot + (size_t)n0 * D_MODEL + k0);
#pragma unroll
    for (int i = 0; i < 16; ++i) {
        const int idx = i * 256 + tid;
        const int rn = idx >> 6, ck = idx & 63;
        outp[(size_t)rn * D_MODEL + ck] = f2bf(Ls[ck][rn]);
    }
}

// ---------------------------------------------------------------------------
// MFMA bf16 GEMM, m97 structure: 128x128 tile, BK=64, global_load_lds(16B),
// chunk-XOR LDS swizzle. MODE 0: qkv -> bf16 Q/K/V with elu1 on Q,K.
// MODE 1: -> fp32 out (final projection).
// ---------------------------------------------------------------------------
template<int MODE>
__global__ __launch_bounds__(256) void mfma_gemm_kernel(
    const unsigned short* __restrict__ A,
    const unsigned short* __restrict__ Bt,
    const float* __restrict__ b0, const float* __restrict__ b1,
    const float* __restrict__ b2,
    void* __restrict__ O0, void* __restrict__ O1, void* __restrict__ O2)
{
    __shared__ __align__(16) unsigned short As[128 * 64];
    __shared__ __align__(16) unsigned short Bs[128 * 64];
    const int tid = threadIdx.x;
    const int wave = tid >> 6, lane = tid & 63;
    const int la = lane & 15, q = lane >> 4;
    const int wm = (wave >> 1) * 64, wn = (wave & 1) * 64;

    int mtile, ntile;
    if (MODE == 0) { ntile = blockIdx.x % 6; mtile = blockIdx.x / 6; }
    else           { ntile = blockIdx.x & 1; mtile = blockIdx.x >> 1; }
    const int m0 = mtile * 128, n0 = ntile * 128;

    const unsigned short* Ab = A  + (size_t)m0 * D_MODEL;
    const unsigned short* Bb = Bt + (size_t)n0 * D_MODEL;

    f32x4 acc[4][4];
#pragma unroll
    for (int i = 0; i < 4; ++i)
#pragma unroll
        for (int j = 0; j < 4; ++j) acc[i][j] = (f32x4){0.f, 0.f, 0.f, 0.f};

    for (int k0 = 0; k0 < D_MODEL; k0 += 64) {
#pragma unroll
        for (int i = 0; i < 4; ++i) {
            const int bslot = i * 256 + wave * 64;
            const int slot = bslot + lane;
            const int m = slot >> 3, s = slot & 7;
            const int g = s ^ (m & 7);
            gld_lds16(Ab + (size_t)m * D_MODEL + k0 + g * 8, &As[bslot * 8]);
            gld_lds16(Bb + (size_t)m * D_MODEL + k0 + g * 8, &Bs[bslot * 8]);
        }
        __syncthreads();

        bf16x8 af[4][2], bfr[4][2];
#pragma unroll
        for (int i = 0; i < 4; ++i) {
#pragma unroll
            for (int kh = 0; kh < 2; ++kh) {
                const int g = kh * 4 + q;
                const int m = wm + i * 16 + la;
                af[i][kh] = *reinterpret_cast<const bf16x8*>(
                    &As[m * 64 + ((g ^ (m & 7)) << 3)]);
                const int n = wn + i * 16 + la;
                bfr[i][kh] = *reinterpret_cast<const bf16x8*>(
                    &Bs[n * 64 + ((g ^ (n & 7)) << 3)]);
            }
        }
#pragma unroll
        for (int mi = 0; mi < 4; ++mi)
#pragma unroll
            for (int ni = 0; ni < 4; ++ni) {
                acc[mi][ni] = __builtin_amdgcn_mfma_f32_16x16x32_bf16(
                    af[mi][0], bfr[ni][0], acc[mi][ni], 0, 0, 0);
                acc[mi][ni] = __builtin_amdgcn_mfma_f32_16x16x32_bf16(
                    af[mi][1], bfr[ni][1], acc[mi][ni], 0, 0, 0);
            }
        __syncthreads();
    }

    // C/D layout: col=lane&15, row=(lane>>4)*4+reg
#pragma unroll
    for (int mi = 0; mi < 4; ++mi) {
#pragma unroll
        for (int ni = 0; ni < 4; ++ni) {
            const int row = m0 + wm + mi * 16 + q * 4;
            const int col = n0 + wn + ni * 16 + la;
            if (MODE == 0) {
                const int which = col >> 8;          // block-uniform
                const int cl = col & 255;
                unsigned short* Out = (unsigned short*)
                    (which == 0 ? O0 : which == 1 ? O1 : O2);
                const float* bias = which == 0 ? b0 : which == 1 ? b1 : b2;
                const int act = (which < 2);
                const float bv = bias[cl];
#pragma unroll
                for (int r = 0; r < 4; ++r) {
                    float v = acc[mi][ni][r] + bv;
                    if (act) v = elu1(v);
                    Out[(size_t)(row + r) * D_MODEL + cl] = f2bf(v);
                }
            } else {
                float* Out = (float*)O0;
                const float bv = b0[col];
#pragma unroll
                for (int r = 0; r < 4; ++r)
                    Out[(size_t)(row + r) * D_MODEL + col] = acc[mi][ni][r] + bv;
            }
        }
    }
}

// ---------------------------------------------------------------------------
// chunksum — R3's VERIFIED fp32 vector version; inputs bf16 (converted at
// staging). P_c[d][m] = sum_t K[t][d]*V[t][m]; Z_c[d] = sum_t K[t][d].
// ---------------------------------------------------------------------------
__global__ __launch_bounds__(256) void chunksum_kernel(
    const unsigned short* __restrict__ Kb, const unsigned short* __restrict__ Vb,
    float* __restrict__ P, float* __restrict__ Zc)
{
    const int tid = threadIdx.x;
    const int c  = blockIdx.x % NCHUNK;
    const int bh = blockIdx.x / NCHUNK;
    const int b = bh / NHEADS, h = bh % NHEADS;

    __shared__ float Ks[CHUNK][DHEAD + 4];  // stride 68: 16B-aligned
    __shared__ float Vs[CHUNK][DHEAD];

    const size_t gbase = ((size_t)(b * TSEQ + c * CHUNK)) * D_MODEL + h * DHEAD;
#pragma unroll
    for (int i = 0; i < 16; ++i) {
        const int idx = i * 256 + tid;
        const int t = idx >> 6, d = idx & 63;
        Ks[t][d] = bf2f(Kb[gbase + (size_t)t * D_MODEL + d]);
        Vs[t][d] = bf2f(Vb[gbase + (size_t)t * D_MODEL + d]);
    }
    __syncthreads();

    const int ty = tid >> 4, tx = tid & 15;
    const int d0 = ty * 4, m0 = tx * 4;
    float4 o0 = {0,0,0,0}, o1 = o0, o2 = o0, o3 = o0;
    for (int t = 0; t < CHUNK; ++t) {
        const float4 k4 = *reinterpret_cast<const float4*>(&Ks[t][d0]);
        const float4 v4 = *reinterpret_cast<const float4*>(&Vs[t][m0]);
        fma4(o0, k4.x, v4);
        fma4(o1, k4.y, v4);
        fma4(o2, k4.z, v4);
        fma4(o3, k4.w, v4);
    }
    float* kvb = P + (size_t)blockIdx.x * (DHEAD * DHEAD);
    *reinterpret_cast<float4*>(&kvb[(d0 + 0) * DHEAD + m0]) = o0;
    *reinterpret_cast<float4*>(&kvb[(d0 + 1) * DHEAD + m0]) = o1;
    *reinterpret_cast<float4*>(&kvb[(d0 + 2) * DHEAD + m0]) = o2;
    *reinterpret_cast<float4*>(&kvb[(d0 + 3) * DHEAD + m0]) = o3;

    if (tid < DHEAD) {
        float z = 0.f;
        for (int t = 0; t < CHUNK; ++t) z += Ks[t][tid];
        Zc[(size_t)blockIdx.x * DHEAD + tid] = z;
    }
}

// ---------------------------------------------------------------------------
// prefix: exclusive scan over chunks; all 32 loads issued before stores.
// ---------------------------------------------------------------------------
__global__ __launch_bounds__(256) void prefix_kernel(
    float* __restrict__ P, float* __restrict__ Zc)
{
    const int tid = threadIdx.x;
    if (blockIdx.x < NBH * 16) {
        const int bh = blockIdx.x >> 4;
        const int e = ((blockIdx.x & 15) << 8) + tid;
        const size_t base = (size_t)bh * NCHUNK * (DHEAD * DHEAD) + e;
        float v[NCHUNK];
#pragma unroll
        for (int c = 0; c < NCHUNK; ++c) v[c] = P[base + (size_t)c * (DHEAD * DHEAD)];
        float s = 0.f;
#pragma unroll
        for (int c = 0; c < NCHUNK; ++c) {
            const float t = v[c];
            P[base + (size_t)c * (DHEAD * DHEAD)] = s;
            s += t;
        }
    } else {
        const int j = ((int)(blockIdx.x - NBH * 16) << 8) + tid;
        if (j < NBH * DHEAD) {
            const int bh = j >> 6, d = j & 63;
            float v[NCHUNK];
#pragma unroll
            for (int c = 0; c < NCHUNK; ++c) v[c] = Zc[(bh * NCHUNK + c) * DHEAD + d];
            float s = 0.f;
#pragma unroll
            for (int c = 0; c < NCHUNK; ++c) {
                const float t = v[c];
                Zc[(bh * NCHUNK + c) * DHEAD + d] = s;
                s += t;
            }
        }
    }
}

// ---------------------------------------------------------------------------
// chunkout — R3's VERIFIED fp32 logic; inputs bf16 (converted at staging),
// S_prev fp32 in [d][m] layout, output bf16.
// ---------------------------------------------------------------------------
__global__ __launch_bounds__(256) void chunkout_kernel(
    const unsigned short* __restrict__ Qb, const unsigned short* __restrict__ Kb,
    const unsigned short* __restrict__ Vb,
    const float* __restrict__ Sx, const float* __restrict__ Zx,
    unsigned short* __restrict__ Ob)
{
    const int tid = threadIdx.x;
    const int c  = blockIdx.x % NCHUNK;
    const int bh = blockIdx.x / NCHUNK;
    const int b = bh / NHEADS, h = bh % NHEADS;

    __shared__ float Qt[DHEAD][CHUNK + 4];    // Qt[d][t]
    __shared__ float KtAt[DHEAD][CHUNK + 4];  // first Kt[d][s], later At[s][t]
    __shared__ float Vs[CHUNK][DHEAD];        // Vs[s][m]
    __shared__ float Ss[DHEAD][DHEAD];        // Sprev[d][m]
    __shared__ float zsh[DHEAD];
    __shared__ float dnm[CHUNK];

    const size_t gbase = ((size_t)(b * TSEQ + c * CHUNK)) * D_MODEL + h * DHEAD;
    const size_t sbase = (size_t)blockIdx.x * (DHEAD * DHEAD);
#pragma unroll
    for (int i = 0; i < 16; ++i) {
        const int idx = i * 256 + tid;
        const int t = idx >> 6, d = idx & 63;
        Qt[d][t]   = bf2f(Qb[gbase + (size_t)t * D_MODEL + d]);
        KtAt[d][t] = bf2f(Kb[gbase + (size_t)t * D_MODEL + d]);
        Vs[t][d]   = bf2f(Vb[gbase + (size_t)t * D_MODEL + d]);
        Ss[t][d]   = Sx[sbase + idx];   // here t indexes the d-dim of S
    }
    if (tid < DHEAD) zsh[tid] = Zx[((size_t)bh * NCHUNK + c) * DHEAD + tid];
    __syncthreads();

    const int ty = tid >> 4, tx = tid & 15;
    const int t0 = ty * 4, s0 = tx * 4;

    float4 a0 = {0,0,0,0}, a1 = a0, a2 = a0, a3 = a0;
    for (int d = 0; d < DHEAD; ++d) {
        const float4 q4 = *reinterpret_cast<const float4*>(&Qt[d][t0]);
        const float4 k4 = *reinterpret_cast<const float4*>(&KtAt[d][s0]);
        fma4(a0, k4.x, q4);
        fma4(a1, k4.y, q4);
        fma4(a2, k4.z, q4);
        fma4(a3, k4.w, q4);
    }
    mask4(a0, s0 + 0, t0);
    mask4(a1, s0 + 1, t0);
    mask4(a2, s0 + 2, t0);
    mask4(a3, s0 + 3, t0);
    __syncthreads();
    *reinterpret_cast<float4*>(&KtAt[s0 + 0][t0]) = a0;
    *reinterpret_cast<float4*>(&KtAt[s0 + 1][t0]) = a1;
    *reinterpret_cast<float4*>(&KtAt[s0 + 2][t0]) = a2;
    *reinterpret_cast<float4*>(&KtAt[s0 + 3][t0]) = a3;
    __syncthreads();

    if (tid < CHUNK) {
        float dv = 0.f;
        for (int s = 0; s < CHUNK; ++s) dv += KtAt[s][tid];
        for (int d = 0; d < DHEAD; ++d) dv = fmaf(Qt[d][tid], zsh[d], dv);
        dnm[tid] = dv + EPSV;
    }
    __syncthreads();

    const int m0 = tx * 4;
    float4 o0 = {0,0,0,0}, o1 = o0, o2 = o0, o3 = o0;
    for (int d = 0; d < DHEAD; ++d) {
        const float4 q4 = *reinterpret_cast<const float4*>(&Qt[d][t0]);
        const float4 s4 = *reinterpret_cast<const float4*>(&Ss[d][m0]);
        fma4(o0, q4.x, s4);
        fma4(o1, q4.y, s4);
        fma4(o2, q4.z, s4);
        fma4(o3, q4.w, s4);
    }
    for (int s = 0; s < CHUNK; ++s) {
        const float4 a4 = *reinterpret_cast<const float4*>(&KtAt[s][t0]);
        const float4 v4 = *reinterpret_cast<const float4*>(&Vs[s][m0]);
        fma4(o0, a4.x, v4);
        fma4(o1, a4.y, v4);
        fma4(o2, a4.z, v4);
        fma4(o3, a4.w, v4);
    }
    const float r0 = 1.f / dnm[t0 + 0];
    const float r1 = 1.f / dnm[t0 + 1];
    const float r2 = 1.f / dnm[t0 + 2];
    const float r3 = 1.f / dnm[t0 + 3];
    ushort4 p0 = { f2bf(o0.x * r0), f2bf(o0.y * r0), f2bf(o0.z * r0), f2bf(o0.w * r0) };
    ushort4 p1 = { f2bf(o1.x * r1), f2bf(o1.y * r1), f2bf(o1.z * r1), f2bf(o1.w * r1) };
    ushort4 p2 = { f2bf(o2.x * r2), f2bf(o2.y * r2), f2bf(o2.z * r2), f2bf(o2.w * r2) };
    ushort4 p3 = { f2bf(o3.x * r3), f2bf(o3.y * r3), f2bf(o3.z * r3), f2bf(o3.w * r3) };
    *reinterpret_cast<ushort4*>(&Ob[gbase + (size_t)(t0 + 0) * D_MODEL + m0]) = p0;
    *reinterpret_cast<ushort4*>(&Ob[gbase + (size_t)(t0 + 1) * D_MODEL + m0]) = p1;
    *reinterpret_cast<ushort4*>(&Ob[gbase + (size_t)(t0 + 2) * D_MODEL + m0]) = p2;
    *reinterpret_cast<ushort4*>(&Ob[gbase + (size_t)(t0 + 3) * D_MODEL + m0]) = p3;
}

extern "C" void kernel_launch(void* const* d_in, const int* in_sizes, int n_in,
                              void* d_out, int out_size, void* d_ws, size_t ws_size,
                              hipStream_t stream)
{
    const float* x  = (const float*)d_in[0];
    const float* Wq = (const float*)d_in[1];
    const float* bq = (const float*)d_in[2];
    const float* Wk = (const float*)d_in[3];
    const float* bk = (const float*)d_in[4];
    const float* Wv = (const float*)d_in[5];
    const float* bv = (const float*)d_in[6];
    const float* Wo = (const float*)d_in[7];
    const float* bo = (const float*)d_in[8];
    float* out = (float*)d_out;

    const size_t NE = (size_t)NTOK * D_MODEL;               // 2M elems
    unsigned short* xb  = (unsigned short*)d_ws;            // 2M bf16
    unsigned short* Wt  = xb + NE;                          // 768*256
    unsigned short* Wot = Wt + 768 * 256;                   // 256*256
    unsigned short* Qb  = Wot + 256 * 256;                  // 2M
    unsigned short* Kb  = Qb + NE;                          // 2M
    unsigned short* Vb  = Kb + NE;                          // 2M
    unsigned short* Ob  = Vb + NE;                          // 2M
    float* P = (float*)(Ob + NE);                           // 16*32*4096 f32 (8MB)
    float* Z = P + (size_t)NBH * NCHUNK * DHEAD * DHEAD;    // 16*32*64 f32

    convert_x_kernel<<<NTOK * D_MODEL / 8 / 256, 256, 0, stream>>>(x, xb);
    convert_w_kernel<<<64, 256, 0, stream>>>(Wq, Wk, Wv, Wo, Wt, Wot);
    mfma_gemm_kernel<0><<<(NTOK / 128) * 6, 256, 0, stream>>>(
        xb, Wt, bq, bk, bv, Qb, Kb, Vb);
    chunksum_kernel<<<NBH * NCHUNK, 256, 0, stream>>>(Kb, Vb, P, Z);
    prefix_kernel<<<NBH * 16 + 4, 256, 0, stream>>>(P, Z);
    chunkout_kernel<<<NBH * NCHUNK, 256, 0, stream>>>(Qb, Kb, Vb, P, Z, Ob);
    mfma_gemm_kernel<1><<<(NTOK / 128) * 2, 256, 0, stream>>>(
        Ob, Wot, bo, nullptr, nullptr, out, nullptr, nullptr);
}

// Round 7
// 116.953 us; speedup vs baseline: 2.0511x; 1.0511x over previous
//
#include <hip/hip_runtime.h>
#include <hip/hip_bf16.h>

#define D_MODEL 256
#define NHEADS 4
#define DHEAD 64
#define BATCH 4
#define TSEQ 2048
#define CHUNK 64
#define NCHUNK (TSEQ / CHUNK)   // 32
#define NTOK (BATCH * TSEQ)     // 8192
#define NBH (BATCH * NHEADS)    // 16
#define EPSV 1e-6f
#define LSTRF 68                // fp32 LDS row stride (verified R6 pattern)

typedef __bf16 bf16x8 __attribute__((ext_vector_type(8)));
typedef float f32x4 __attribute__((ext_vector_type(4)));
typedef unsigned short us8 __attribute__((ext_vector_type(8)));

__device__ __forceinline__ float elu1(float a) {
    return a > 0.0f ? a + 1.0f : __expf(a);
}

__device__ __forceinline__ unsigned short f2bf(float f) {
    __hip_bfloat16 h = __float2bfloat16(f);   // RNE
    return __builtin_bit_cast(unsigned short, h);
}

__device__ __forceinline__ float bf2f(unsigned short u) {
    return __bfloat162float(__builtin_bit_cast(__hip_bfloat16, u));
}

// Build a bf16x8 MFMA fragment from 8 consecutive fp32 values (16B-aligned).
__device__ __forceinline__ bf16x8 frag8(const float* p) {
    const float4 x = *reinterpret_cast<const float4*>(p);
    const float4 y = *reinterpret_cast<const float4*>(p + 4);
    us8 u;
    u[0] = f2bf(x.x); u[1] = f2bf(x.y); u[2] = f2bf(x.z); u[3] = f2bf(x.w);
    u[4] = f2bf(y.x); u[5] = f2bf(y.y); u[6] = f2bf(y.z); u[7] = f2bf(y.w);
    return __builtin_bit_cast(bf16x8, u);
}

// async global->LDS, 16B per lane; lds ptr must be wave-uniform base.
__device__ __forceinline__ void gld_lds16(const void* g, void* l) {
    __builtin_amdgcn_global_load_lds(
        (const __attribute__((address_space(1))) void*)g,
        (__attribute__((address_space(3))) void*)l, 16, 0, 0);
}

// ---------------------------------------------------------------------------
// convert x (fp32) -> xb (bf16)
// ---------------------------------------------------------------------------
__global__ __launch_bounds__(256) void convert_x_kernel(
    const float* __restrict__ x, unsigned short* __restrict__ xb)
{
    const int i = (blockIdx.x * 256 + threadIdx.x) * 8;
    const float4 a = *reinterpret_cast<const float4*>(&x[i]);
    const float4 b = *reinterpret_cast<const float4*>(&x[i + 4]);
    ushort4 u0 = { f2bf(a.x), f2bf(a.y), f2bf(a.z), f2bf(a.w) };
    ushort4 u1 = { f2bf(b.x), f2bf(b.y), f2bf(b.z), f2bf(b.w) };
    *reinterpret_cast<ushort4*>(&xb[i]) = u0;
    *reinterpret_cast<ushort4*>(&xb[i + 4]) = u1;
}

// ---------------------------------------------------------------------------
// transpose-convert W[k][n] fp32 -> Wt[n][k] bf16 (Wq,Wk,Wv -> 768 rows; Wo).
// ---------------------------------------------------------------------------
__global__ __launch_bounds__(256) void convert_w_kernel(
    const float* __restrict__ Wq, const float* __restrict__ Wk,
    const float* __restrict__ Wv, const float* __restrict__ Wo,
    unsigned short* __restrict__ Wt, unsigned short* __restrict__ Wot)
{
    __shared__ float Ls[64][65];
    const int tid = threadIdx.x;
    const int wi = blockIdx.x >> 4;
    const int ti = blockIdx.x & 15;
    const int k0 = (ti >> 2) * 64, n0 = (ti & 3) * 64;
    const float* W = wi == 0 ? Wq : wi == 1 ? Wk : wi == 2 ? Wv : Wo;
#pragma unroll
    for (int i = 0; i < 16; ++i) {
        const int idx = i * 256 + tid;
        const int r = idx >> 6, c = idx & 63;
        Ls[r][c] = W[(size_t)(k0 + r) * D_MODEL + n0 + c];
    }
    __syncthreads();
    unsigned short* outp = (wi < 3) ? (Wt + (size_t)(wi * 256 + n0) * D_MODEL + k0)
                                    : (Wot + (size_t)n0 * D_MODEL + k0);
#pragma unroll
    for (int i = 0; i < 16; ++i) {
        const int idx = i * 256 + tid;
        const int rn = idx >> 6, ck = idx & 63;
        outp[(size_t)rn * D_MODEL + ck] = f2bf(Ls[ck][rn]);
    }
}

// ---------------------------------------------------------------------------
// MFMA bf16 GEMM, m97 structure (verified): 128x128 tile, BK=64,
// global_load_lds(16B), chunk-XOR LDS swizzle.
// MODE 0: qkv -> bf16 Q/K/V with elu1 on Q,K.  MODE 1: -> fp32 out.
// ---------------------------------------------------------------------------
template<int MODE>
__global__ __launch_bounds__(256) void mfma_gemm_kernel(
    const unsigned short* __restrict__ A,
    const unsigned short* __restrict__ Bt,
    const float* __restrict__ b0, const float* __restrict__ b1,
    const float* __restrict__ b2,
    void* __restrict__ O0, void* __restrict__ O1, void* __restrict__ O2)
{
    __shared__ __align__(16) unsigned short As[128 * 64];
    __shared__ __align__(16) unsigned short Bs[128 * 64];
    const int tid = threadIdx.x;
    const int wave = tid >> 6, lane = tid & 63;
    const int la = lane & 15, q = lane >> 4;
    const int wm = (wave >> 1) * 64, wn = (wave & 1) * 64;

    int mtile, ntile;
    if (MODE == 0) { ntile = blockIdx.x % 6; mtile = blockIdx.x / 6; }
    else           { ntile = blockIdx.x & 1; mtile = blockIdx.x >> 1; }
    const int m0 = mtile * 128, n0 = ntile * 128;

    const unsigned short* Ab = A  + (size_t)m0 * D_MODEL;
    const unsigned short* Bb = Bt + (size_t)n0 * D_MODEL;

    f32x4 acc[4][4];
#pragma unroll
    for (int i = 0; i < 4; ++i)
#pragma unroll
        for (int j = 0; j < 4; ++j) acc[i][j] = (f32x4){0.f, 0.f, 0.f, 0.f};

    for (int k0 = 0; k0 < D_MODEL; k0 += 64) {
#pragma unroll
        for (int i = 0; i < 4; ++i) {
            const int bslot = i * 256 + wave * 64;
            const int slot = bslot + lane;
            const int m = slot >> 3, s = slot & 7;
            const int g = s ^ (m & 7);
            gld_lds16(Ab + (size_t)m * D_MODEL + k0 + g * 8, &As[bslot * 8]);
            gld_lds16(Bb + (size_t)m * D_MODEL + k0 + g * 8, &Bs[bslot * 8]);
        }
        __syncthreads();

        bf16x8 af[4][2], bfr[4][2];
#pragma unroll
        for (int i = 0; i < 4; ++i) {
#pragma unroll
            for (int kh = 0; kh < 2; ++kh) {
                const int g = kh * 4 + q;
                const int m = wm + i * 16 + la;
                af[i][kh] = *reinterpret_cast<const bf16x8*>(
                    &As[m * 64 + ((g ^ (m & 7)) << 3)]);
                const int n = wn + i * 16 + la;
                bfr[i][kh] = *reinterpret_cast<const bf16x8*>(
                    &Bs[n * 64 + ((g ^ (n & 7)) << 3)]);
            }
        }
#pragma unroll
        for (int mi = 0; mi < 4; ++mi)
#pragma unroll
            for (int ni = 0; ni < 4; ++ni) {
                acc[mi][ni] = __builtin_amdgcn_mfma_f32_16x16x32_bf16(
                    af[mi][0], bfr[ni][0], acc[mi][ni], 0, 0, 0);
                acc[mi][ni] = __builtin_amdgcn_mfma_f32_16x16x32_bf16(
                    af[mi][1], bfr[ni][1], acc[mi][ni], 0, 0, 0);
            }
        __syncthreads();
    }

    // C/D layout: col=lane&15, row=(lane>>4)*4+reg
#pragma unroll
    for (int mi = 0; mi < 4; ++mi) {
#pragma unroll
        for (int ni = 0; ni < 4; ++ni) {
            const int row = m0 + wm + mi * 16 + q * 4;
            const int col = n0 + wn + ni * 16 + la;
            if (MODE == 0) {
                const int which = col >> 8;          // block-uniform
                const int cl = col & 255;
                unsigned short* Out = (unsigned short*)
                    (which == 0 ? O0 : which == 1 ? O1 : O2);
                const float* bias = which == 0 ? b0 : which == 1 ? b1 : b2;
                const int act = (which < 2);
                const float bv = bias[cl];
#pragma unroll
                for (int r = 0; r < 4; ++r) {
                    float v = acc[mi][ni][r] + bv;
                    if (act) v = elu1(v);
                    Out[(size_t)(row + r) * D_MODEL + cl] = f2bf(v);
                }
            } else {
                float* Out = (float*)O0;
                const float bv = b0[col];
#pragma unroll
                for (int r = 0; r < 4; ++r)
                    Out[(size_t)(row + r) * D_MODEL + col] = acc[mi][ni][r] + bv;
            }
        }
    }
}

// ---------------------------------------------------------------------------
// chunksum (MFMA, verified-class staging):
//   Pt_c[m][d] = sum_t V[t][m] K[t][d]   ( = (K^T V)^T = S^T )
//   Z_c[d]     = sum_t K[t][d]
// Staging: fp32 b32 transpose-scatter (exact R6-chunkout op class).
// Fragments: 2x float4 LDS reads + VALU cvt -> bf16x8.
// ---------------------------------------------------------------------------
__global__ __launch_bounds__(256) void chunksum_kernel(
    const unsigned short* __restrict__ Kb, const unsigned short* __restrict__ Vb,
    float* __restrict__ Pt, float* __restrict__ Zc)
{
    __shared__ float Ktf[DHEAD * LSTRF];   // Ktf[d][t]
    __shared__ float Vtf[DHEAD * LSTRF];   // Vtf[m][t]
    const int tid = threadIdx.x;
    const int c  = blockIdx.x % NCHUNK;
    const int bh = blockIdx.x / NCHUNK;
    const int b = bh / NHEADS, h = bh % NHEADS;
    const size_t gbase = ((size_t)(b * TSEQ + c * CHUNK)) * D_MODEL + h * DHEAD;

#pragma unroll
    for (int i = 0; i < 16; ++i) {
        const int idx = i * 256 + tid;
        const int t = idx >> 6, d = idx & 63;
        Ktf[d * LSTRF + t] = bf2f(Kb[gbase + (size_t)t * D_MODEL + d]);
        Vtf[d * LSTRF + t] = bf2f(Vb[gbase + (size_t)t * D_MODEL + d]);
    }
    __syncthreads();

    const int wave = tid >> 6, lane = tid & 63;
    const int la = lane & 15, q = lane >> 4;
    const int wm = (wave >> 1) * 32, wn = (wave & 1) * 32;   // m rows, d cols

    f32x4 acc[2][2];
#pragma unroll
    for (int i = 0; i < 2; ++i)
#pragma unroll
        for (int j = 0; j < 2; ++j) acc[i][j] = (f32x4){0.f, 0.f, 0.f, 0.f};

#pragma unroll
    for (int ks = 0; ks < 2; ++ks) {
        const int ko = ks * 32 + q * 8;                       // k = t
        const bf16x8 a0  = frag8(&Vtf[(wm + la) * LSTRF + ko]);
        const bf16x8 a1  = frag8(&Vtf[(wm + 16 + la) * LSTRF + ko]);
        const bf16x8 bb0 = frag8(&Ktf[(wn + la) * LSTRF + ko]);
        const bf16x8 bb1 = frag8(&Ktf[(wn + 16 + la) * LSTRF + ko]);
        acc[0][0] = __builtin_amdgcn_mfma_f32_16x16x32_bf16(a0, bb0, acc[0][0], 0, 0, 0);
        acc[0][1] = __builtin_amdgcn_mfma_f32_16x16x32_bf16(a0, bb1, acc[0][1], 0, 0, 0);
        acc[1][0] = __builtin_amdgcn_mfma_f32_16x16x32_bf16(a1, bb0, acc[1][0], 0, 0, 0);
        acc[1][1] = __builtin_amdgcn_mfma_f32_16x16x32_bf16(a1, bb1, acc[1][1], 0, 0, 0);
    }

    float* Pb = Pt + (size_t)blockIdx.x * (DHEAD * DHEAD);
#pragma unroll
    for (int mi = 0; mi < 2; ++mi)
#pragma unroll
        for (int ni = 0; ni < 2; ++ni) {
            const int row = wm + mi * 16 + q * 4;   // m
            const int col = wn + ni * 16 + la;      // d
#pragma unroll
            for (int r = 0; r < 4; ++r)
                Pb[(row + r) * DHEAD + col] = acc[mi][ni][r];
        }

    if (tid < DHEAD) {
        float z = 0.f;
        for (int t = 0; t < CHUNK; ++t) z += Ktf[tid * LSTRF + t];
        Zc[(size_t)blockIdx.x * DHEAD + tid] = z;
    }
}

// ---------------------------------------------------------------------------
// prefix: exclusive scan over chunks; all 32 loads issued before stores.
// ---------------------------------------------------------------------------
__global__ __launch_bounds__(256) void prefix_kernel(
    float* __restrict__ P, float* __restrict__ Zc)
{
    const int tid = threadIdx.x;
    if (blockIdx.x < NBH * 16) {
        const int bh = blockIdx.x >> 4;
        const int e = ((blockIdx.x & 15) << 8) + tid;
        const size_t base = (size_t)bh * NCHUNK * (DHEAD * DHEAD) + e;
        float v[NCHUNK];
#pragma unroll
        for (int c = 0; c < NCHUNK; ++c) v[c] = P[base + (size_t)c * (DHEAD * DHEAD)];
        float s = 0.f;
#pragma unroll
        for (int c = 0; c < NCHUNK; ++c) {
            const float t = v[c];
            P[base + (size_t)c * (DHEAD * DHEAD)] = s;
            s += t;
        }
    } else {
        const int j = ((int)(blockIdx.x - NBH * 16) << 8) + tid;
        if (j < NBH * DHEAD) {
            const int bh = j >> 6, d = j & 63;
            float v[NCHUNK];
#pragma unroll
            for (int c = 0; c < NCHUNK; ++c) v[c] = Zc[(bh * NCHUNK + c) * DHEAD + d];
            float s = 0.f;
#pragma unroll
            for (int c = 0; c < NCHUNK; ++c) {
                const float t = v[c];
                Zc[(bh * NCHUNK + c) * DHEAD + d] = s;
                s += t;
            }
        }
    }
}

// ---------------------------------------------------------------------------
// chunkout (MFMA, verified-class staging):
//   A = tril(Q K^T);  O[t][m] = (Q S_prev + A V)[t][m] / denom[t] -> bf16
//   Pt (= S_prev^T[m][d], exclusive-scanned) B-frags read from GLOBAL.
// ---------------------------------------------------------------------------
__global__ __launch_bounds__(256) void chunkout_kernel(
    const unsigned short* __restrict__ Qb, const unsigned short* __restrict__ Kb,
    const unsigned short* __restrict__ Vb,
    const float* __restrict__ Pt, const float* __restrict__ Zx,
    unsigned short* __restrict__ Ob)
{
    __shared__ float Qs[CHUNK * LSTRF];    // Qs[t][d]
    __shared__ float Ks[CHUNK * LSTRF];    // Ks[s][d]
    __shared__ float Vtf[DHEAD * LSTRF];   // Vtf[m][s]
    __shared__ float At[CHUNK * LSTRF];    // At[t][s] masked QK^T, fp32
    __shared__ float zsh[DHEAD];
    __shared__ float dnm[CHUNK];

    const int tid = threadIdx.x;
    const int c  = blockIdx.x % NCHUNK;
    const int bh = blockIdx.x / NCHUNK;
    const int b = bh / NHEADS, h = bh % NHEADS;
    const size_t gbase = ((size_t)(b * TSEQ + c * CHUNK)) * D_MODEL + h * DHEAD;
    const float* Pp = Pt + (size_t)blockIdx.x * (DHEAD * DHEAD);

#pragma unroll
    for (int i = 0; i < 16; ++i) {
        const int idx = i * 256 + tid;
        const int t = idx >> 6, d = idx & 63;
        const float qv = bf2f(Qb[gbase + (size_t)t * D_MODEL + d]);
        const float kv = bf2f(Kb[gbase + (size_t)t * D_MODEL + d]);
        const float vv = bf2f(Vb[gbase + (size_t)t * D_MODEL + d]);
        Qs[t * LSTRF + d]  = qv;    // row-major
        Ks[t * LSTRF + d]  = kv;    // row-major
        Vtf[d * LSTRF + t] = vv;    // transposed (b32 scatter, verified class)
    }
    if (tid < DHEAD) zsh[tid] = Zx[((size_t)bh * NCHUNK + c) * DHEAD + tid];
    __syncthreads();

    const int wave = tid >> 6, lane = tid & 63;
    const int la = lane & 15, q = lane >> 4;
    const int wt = (wave >> 1) * 32, wn = (wave & 1) * 32;

    // phase 1: A = Q K^T  (A-frag: Q rows, k=d; B-frag: K rows, k=d)
    f32x4 acc[2][2];
#pragma unroll
    for (int i = 0; i < 2; ++i)
#pragma unroll
        for (int j = 0; j < 2; ++j) acc[i][j] = (f32x4){0.f, 0.f, 0.f, 0.f};
#pragma unroll
    for (int ks = 0; ks < 2; ++ks) {
        const int ko = ks * 32 + q * 8;
        const bf16x8 a0  = frag8(&Qs[(wt + la) * LSTRF + ko]);
        const bf16x8 a1  = frag8(&Qs[(wt + 16 + la) * LSTRF + ko]);
        const bf16x8 bb0 = frag8(&Ks[(wn + la) * LSTRF + ko]);
        const bf16x8 bb1 = frag8(&Ks[(wn + 16 + la) * LSTRF + ko]);
        acc[0][0] = __builtin_amdgcn_mfma_f32_16x16x32_bf16(a0, bb0, acc[0][0], 0, 0, 0);
        acc[0][1] = __builtin_amdgcn_mfma_f32_16x16x32_bf16(a0, bb1, acc[0][1], 0, 0, 0);
        acc[1][0] = __builtin_amdgcn_mfma_f32_16x16x32_bf16(a1, bb0, acc[1][0], 0, 0, 0);
        acc[1][1] = __builtin_amdgcn_mfma_f32_16x16x32_bf16(a1, bb1, acc[1][1], 0, 0, 0);
    }
    // mask in-register, store fp32 At[t][s] (b32 stores, verified class)
#pragma unroll
    for (int mi = 0; mi < 2; ++mi)
#pragma unroll
        for (int ni = 0; ni < 2; ++ni) {
            const int t0 = wt + mi * 16 + q * 4;
            const int s  = wn + ni * 16 + la;
#pragma unroll
            for (int r = 0; r < 4; ++r)
                At[(t0 + r) * LSTRF + s] = (s <= t0 + r) ? acc[mi][ni][r] : 0.f;
        }
    __syncthreads();

    // phase 2: denom[t] = rowsum(A) + Q . Z_prev + eps
    if (tid < CHUNK) {
        float dv = 0.f;
        for (int s = 0; s < CHUNK; ++s) dv += At[tid * LSTRF + s];
        for (int d = 0; d < DHEAD; ++d) dv = fmaf(Qs[tid * LSTRF + d], zsh[d], dv);
        dnm[tid] = dv + EPSV;
    }
    __syncthreads();

    // phase 3: O = Q @ S_prev + A @ V
    f32x4 o[2][2];
#pragma unroll
    for (int i = 0; i < 2; ++i)
#pragma unroll
        for (int j = 0; j < 2; ++j) o[i][j] = (f32x4){0.f, 0.f, 0.f, 0.f};
#pragma unroll
    for (int ks = 0; ks < 2; ++ks) {
        const int ko = ks * 32 + q * 8;                       // k = d
        const bf16x8 a0  = frag8(&Qs[(wt + la) * LSTRF + ko]);
        const bf16x8 a1  = frag8(&Qs[(wt + 16 + la) * LSTRF + ko]);
        const bf16x8 bb0 = frag8(&Pp[(wn + la) * DHEAD + ko]);        // global
        const bf16x8 bb1 = frag8(&Pp[(wn + 16 + la) * DHEAD + ko]);   // global
        o[0][0] = __builtin_amdgcn_mfma_f32_16x16x32_bf16(a0, bb0, o[0][0], 0, 0, 0);
        o[0][1] = __builtin_amdgcn_mfma_f32_16x16x32_bf16(a0, bb1, o[0][1], 0, 0, 0);
        o[1][0] = __builtin_amdgcn_mfma_f32_16x16x32_bf16(a1, bb0, o[1][0], 0, 0, 0);
        o[1][1] = __builtin_amdgcn_mfma_f32_16x16x32_bf16(a1, bb1, o[1][1], 0, 0, 0);
    }
#pragma unroll
    for (int ks = 0; ks < 2; ++ks) {
        const int ko = ks * 32 + q * 8;                       // k = s
        const bf16x8 a0  = frag8(&At[(wt + la) * LSTRF + ko]);
        const bf16x8 a1  = frag8(&At[(wt + 16 + la) * LSTRF + ko]);
        const bf16x8 bb0 = frag8(&Vtf[(wn + la) * LSTRF + ko]);
        const bf16x8 bb1 = frag8(&Vtf[(wn + 16 + la) * LSTRF + ko]);
        o[0][0] = __builtin_amdgcn_mfma_f32_16x16x32_bf16(a0, bb0, o[0][0], 0, 0, 0);
        o[0][1] = __builtin_amdgcn_mfma_f32_16x16x32_bf16(a0, bb1, o[0][1], 0, 0, 0);
        o[1][0] = __builtin_amdgcn_mfma_f32_16x16x32_bf16(a1, bb0, o[1][0], 0, 0, 0);
        o[1][1] = __builtin_amdgcn_mfma_f32_16x16x32_bf16(a1, bb1, o[1][1], 0, 0, 0);
    }

    // epilogue: divide + bf16 scalar stores (verified class via qkv MODE 0)
#pragma unroll
    for (int mi = 0; mi < 2; ++mi)
#pragma unroll
        for (int ni = 0; ni < 2; ++ni) {
            const int t0 = wt + mi * 16 + q * 4;
            const int m  = wn + ni * 16 + la;
#pragma unroll
            for (int r = 0; r < 4; ++r) {
                const float v = o[mi][ni][r] / dnm[t0 + r];
                Ob[gbase + (size_t)(t0 + r) * D_MODEL + m] = f2bf(v);
            }
        }
}

extern "C" void kernel_launch(void* const* d_in, const int* in_sizes, int n_in,
                              void* d_out, int out_size, void* d_ws, size_t ws_size,
                              hipStream_t stream)
{
    const float* x  = (const float*)d_in[0];
    const float* Wq = (const float*)d_in[1];
    const float* bq = (const float*)d_in[2];
    const float* Wk = (const float*)d_in[3];
    const float* bk = (const float*)d_in[4];
    const float* Wv = (const float*)d_in[5];
    const float* bv = (const float*)d_in[6];
    const float* Wo = (const float*)d_in[7];
    const float* bo = (const float*)d_in[8];
    float* out = (float*)d_out;

    const size_t NE = (size_t)NTOK * D_MODEL;               // 2M elems
    unsigned short* xb  = (unsigned short*)d_ws;            // 2M bf16
    unsigned short* Wt  = xb + NE;                          // 768*256
    unsigned short* Wot = Wt + 768 * 256;                   // 256*256
    unsigned short* Qb  = Wot + 256 * 256;                  // 2M
    unsigned short* Kb  = Qb + NE;                          // 2M
    unsigned short* Vb  = Kb + NE;                          // 2M
    unsigned short* Ob  = Vb + NE;                          // 2M
    float* P = (float*)(Ob + NE);                           // 16*32*4096 f32 (8MB)
    float* Z = P + (size_t)NBH * NCHUNK * DHEAD * DHEAD;    // 16*32*64 f32

    convert_x_kernel<<<NTOK * D_MODEL / 8 / 256, 256, 0, stream>>>(x, xb);
    convert_w_kernel<<<64, 256, 0, stream>>>(Wq, Wk, Wv, Wo, Wt, Wot);
    mfma_gemm_kernel<0><<<(NTOK / 128) * 6, 256, 0, stream>>>(
        xb, Wt, bq, bk, bv, Qb, Kb, Vb);
    chunksum_kernel<<<NBH * NCHUNK, 256, 0, stream>>>(Kb, Vb, P, Z);
    prefix_kernel<<<NBH * 16 + 4, 256, 0, stream>>>(P, Z);
    chunkout_kernel<<<NBH * NCHUNK, 256, 0, stream>>>(Qb, Kb, Vb, P, Z, Ob);
    mfma_gemm_kernel<1><<<(NTOK / 128) * 2, 256, 0, stream>>>(
        Ob, Wot, bo, nullptr, nullptr, out, nullptr, nullptr);
}